// Round 1
// baseline (2637.694 us; speedup 1.0000x reference)
//
#include <hip/hip_runtime.h>
#include <cstdint>
#include <cstddef>

// ---------------- constants ----------------
#define KB   8
#define KS   512
#define KD   1024
#define KH   16
#define KDH  64
#define KE   8
#define KDFF 4096
#define KN   4096      // B*S tokens
#define KCAP 1280      // ceil(2*4096/8*1.25)
#define KCHB 16        // attention bh per chunk
#define KNCH 8         // 128 / KCHB

typedef unsigned short u16;
typedef __bf16 bf16x8 __attribute__((ext_vector_type(8)));
typedef float  f32x4  __attribute__((ext_vector_type(4)));

__device__ __forceinline__ u16 f2bf(float f){
  unsigned u = __builtin_bit_cast(unsigned, f);
  u = (u + 0x7FFFu + ((u >> 16) & 1u)) >> 16;   // RNE
  return (u16)u;
}
__device__ __forceinline__ float bf2f(u16 h){
  unsigned u = ((unsigned)h) << 16;
  return __builtin_bit_cast(float, u);
}
__device__ __forceinline__ void split3v(float f, unsigned short &a, unsigned short &b, unsigned short &c){
  a = f2bf(f);
  float r = f - bf2f(a);
  b = f2bf(r);
  c = f2bf(r - bf2f(b));
}
__device__ __forceinline__ bf16x8 ld8(const u16* p){
  uint4 v = *(const uint4*)p;
  return __builtin_bit_cast(bf16x8, v);
}

// ---------------- GEMM (NT, wave = 64x64 tile, 16x16x32 bf16 MFMA) ----------------
// S3=true: A,B given as 3 bf16 planes (hi/mid/lo); 6-term product ~ fp32 accuracy.
struct GArgs {
  const u16 *Ah, *Am, *Al;
  const u16 *Bh, *Bm, *Bl;
  long lda, sA, ldb, sB;         // element strides
  const float* bias; long biasStride;
  float* outF;
  u16 *o0, *o1, *o2;
  int K, mode, chunkBase;
  float scale;
};

template<bool S3>
__launch_bounds__(64)
__global__ void gemm_nt(GArgs g){
  const int lane = threadIdx.x;
  const int quad = lane >> 4;
  const int r    = lane & 15;
  const int z    = blockIdx.z;
  const long m0  = (long)blockIdx.y * 64;
  const long n0  = (long)blockIdx.x * 64;
  const u16* Ah = g.Ah + (long)z * g.sA;
  const u16* Bh = g.Bh + (long)z * g.sB;
  const u16* Am = S3 ? (g.Am + (long)z * g.sA) : nullptr;
  const u16* Al = S3 ? (g.Al + (long)z * g.sA) : nullptr;
  const u16* Bm = S3 ? (g.Bm + (long)z * g.sB) : nullptr;
  const u16* Bl = S3 ? (g.Bl + (long)z * g.sB) : nullptr;
  f32x4 acc[4][4] = {};
  const long ko = quad * 8;
  for (int kt = 0; kt < g.K; kt += 32){
    bf16x8 a0[4], a1[4], a2[4], c0[4], c1[4], c2[4];
#pragma unroll
    for (int i = 0; i < 4; ++i){
      long row = m0 + i*16 + r;
      a0[i] = ld8(Ah + row*g.lda + kt + ko);
      if (S3){
        a1[i] = ld8(Am + row*g.lda + kt + ko);
        a2[i] = ld8(Al + row*g.lda + kt + ko);
      }
    }
#pragma unroll
    for (int j = 0; j < 4; ++j){
      long col = n0 + j*16 + r;
      c0[j] = ld8(Bh + col*g.ldb + kt + ko);
      if (S3){
        c1[j] = ld8(Bm + col*g.ldb + kt + ko);
        c2[j] = ld8(Bl + col*g.ldb + kt + ko);
      }
    }
#pragma unroll
    for (int i = 0; i < 4; ++i)
#pragma unroll
      for (int j = 0; j < 4; ++j){
        acc[i][j] = __builtin_amdgcn_mfma_f32_16x16x32_bf16(a0[i], c0[j], acc[i][j], 0, 0, 0);
        if (S3){
          acc[i][j] = __builtin_amdgcn_mfma_f32_16x16x32_bf16(a0[i], c1[j], acc[i][j], 0, 0, 0);
          acc[i][j] = __builtin_amdgcn_mfma_f32_16x16x32_bf16(a1[i], c0[j], acc[i][j], 0, 0, 0);
          acc[i][j] = __builtin_amdgcn_mfma_f32_16x16x32_bf16(a0[i], c2[j], acc[i][j], 0, 0, 0);
          acc[i][j] = __builtin_amdgcn_mfma_f32_16x16x32_bf16(a2[i], c0[j], acc[i][j], 0, 0, 0);
          acc[i][j] = __builtin_amdgcn_mfma_f32_16x16x32_bf16(a1[i], c1[j], acc[i][j], 0, 0, 0);
        }
      }
  }
  // epilogue: C/D layout col=lane&15, row=quad*4+reg
#pragma unroll
  for (int i = 0; i < 4; ++i){
#pragma unroll
    for (int rr = 0; rr < 4; ++rr){
      long row = m0 + i*16 + quad*4 + rr;
#pragma unroll
      for (int j = 0; j < 4; ++j){
        long col = n0 + j*16 + r;
        float v = acc[i][j][rr];
        switch (g.mode){
          case 0: case 1: {       // qkv proj -> head layout, 3-plane split (+bias)
            v += g.bias[col];
            long b = row >> 9, s = row & 511;
            long h = col >> 6, d = col & 63;
            long idx = (g.mode == 0) ? (((b*KH + h)*KS + s)*KDH + d)     // (B,H,S,dh)
                                     : (((b*KH + h)*KDH + d)*KS + s);   // (B,H,dh,S)
            unsigned short x, y, w; split3v(v, x, y, w);
            g.o0[idx] = x; g.o1[idx] = y; g.o2[idx] = w;
            break;
          }
          case 2: {               // scores (scaled, fp32)
            g.outF[((long)z*KS + row)*KS + col] = v * g.scale;
            break;
          }
          case 3: {               // PV out -> (B,S,D), 3-plane split
            int bh = g.chunkBase + z;
            long b = bh >> 4, h = bh & 15;
            long idx = (b*KS + row)*KD + h*KDH + col;
            unsigned short x, y, w; split3v(v, x, y, w);
            g.o0[idx] = x; g.o1[idx] = y; g.o2[idx] = w;
            break;
          }
          case 4: {               // out-proj: +bias, fp32 linear
            v += g.bias[col];
            g.outF[row*KD + col] = v;
            break;
          }
          case 5: {               // FFN1: +b1, gelu(tanh approx), bf16
            v += g.bias[(long)z*g.biasStride + col];
            float u = v + 0.044715f*v*v*v;
            v = 0.5f*v*(1.0f + tanhf(0.7978845608028654f*u));
            g.o0[((long)z*KCAP + row)*KDFF + col] = f2bf(v);
            break;
          }
          default: {              // FFN2: +b2, bf16
            v += g.bias[(long)z*g.biasStride + col];
            g.o0[((long)z*KCAP + row)*KD + col] = f2bf(v);
            break;
          }
        }
      }
    }
  }
}

// ---------------- prep kernels ----------------
__global__ void split3k(const float* __restrict__ x, u16* __restrict__ h, u16* __restrict__ m,
                        u16* __restrict__ l, long n4){
  long i = (long)blockIdx.x*blockDim.x + threadIdx.x;
  if (i >= n4) return;
  float4 v = ((const float4*)x)[i];
  ushort4 a, b, c;
  split3v(v.x, a.x, b.x, c.x);
  split3v(v.y, a.y, b.y, c.y);
  split3v(v.z, a.z, b.z, c.z);
  split3v(v.w, a.w, b.w, c.w);
  ((ushort4*)h)[i] = a; ((ushort4*)m)[i] = b; ((ushort4*)l)[i] = c;
}

// batched transpose: in (z,R,C) f32 -> out (z,C,R) bf16
__global__ void trans_b(const float* __restrict__ in, u16* __restrict__ outp, int R, int Cc){
  __shared__ float tile[32][33];
  long z = blockIdx.z;
  const float* ip = in + z*(long)R*Cc;
  u16* op = outp + z*(long)R*Cc;
  int c0 = blockIdx.x*32, r0 = blockIdx.y*32;
  int tx = threadIdx.x, ty = threadIdx.y;
  for (int rr = ty; rr < 32; rr += 8)
    tile[rr][tx] = ip[(long)(r0+rr)*Cc + c0 + tx];
  __syncthreads();
  for (int cc = ty; cc < 32; cc += 8)
    op[(long)(c0+cc)*R + r0 + tx] = f2bf(tile[tx][cc]);
}

// ---------------- softmax over 512-wide rows -> 3-plane bf16 P ----------------
__launch_bounds__(64)
__global__ void softmax3(const float* __restrict__ scores, u16* __restrict__ ph,
                         u16* __restrict__ pm, u16* __restrict__ pl){
  long row = blockIdx.x;
  const float* rp = scores + row * KS;
  int lane = threadIdx.x;
  float4 a = ((const float4*)rp)[lane*2];
  float4 b = ((const float4*)rp)[lane*2 + 1];
  float vv[8] = {a.x,a.y,a.z,a.w,b.x,b.y,b.z,b.w};
  float m = vv[0];
#pragma unroll
  for (int t = 1; t < 8; ++t) m = fmaxf(m, vv[t]);
  for (int off = 32; off; off >>= 1) m = fmaxf(m, __shfl_xor(m, off));
  float s = 0.f;
#pragma unroll
  for (int t = 0; t < 8; ++t){ vv[t] = expf(vv[t] - m); s += vv[t]; }
  for (int off = 32; off; off >>= 1) s += __shfl_xor(s, off);
  float inv = 1.0f / s;
  unsigned short hh[8], mm[8], ll[8];
#pragma unroll
  for (int t = 0; t < 8; ++t){
    float p = vv[t] * inv;
    split3v(p, hh[t], mm[t], ll[t]);
  }
  ushort4* dh = (ushort4*)(ph + row*KS + lane*8);
  dh[0] = make_ushort4(hh[0],hh[1],hh[2],hh[3]);
  dh[1] = make_ushort4(hh[4],hh[5],hh[6],hh[7]);
  ushort4* dm = (ushort4*)(pm + row*KS + lane*8);
  dm[0] = make_ushort4(mm[0],mm[1],mm[2],mm[3]);
  dm[1] = make_ushort4(mm[4],mm[5],mm[6],mm[7]);
  ushort4* dl = (ushort4*)(pl + row*KS + lane*8);
  dl[0] = make_ushort4(ll[0],ll[1],ll[2],ll[3]);
  dl[1] = make_ushort4(ll[4],ll[5],ll[6],ll[7]);
}

// ---------------- LN1 + router (fp32 exact) ----------------
__launch_bounds__(256)
__global__ void ln1_router(const float* __restrict__ q, const float* __restrict__ attn,
    const float* __restrict__ lnw, const float* __restrict__ lnb, const float* __restrict__ rw,
    float* __restrict__ x1, u16* __restrict__ x1b,
    int* __restrict__ idx0, int* __restrict__ idx1, float* __restrict__ gate0, float* __restrict__ gate1,
    float* __restrict__ psum, float* __restrict__ lse2){
  const int t = blockIdx.x, tid = threadIdx.x;
  const int lane = tid & 63, wid = tid >> 6;
  float4 xv = ((const float4*)(q    + (long)t*KD))[tid];
  float4 av = ((const float4*)(attn + (long)t*KD))[tid];
  xv.x += av.x; xv.y += av.y; xv.z += av.z; xv.w += av.w;
  float s  = xv.x + xv.y + xv.z + xv.w;
  float ss = xv.x*xv.x + xv.y*xv.y + xv.z*xv.z + xv.w*xv.w;
  for (int off = 32; off; off >>= 1){ s += __shfl_xor(s, off); ss += __shfl_xor(ss, off); }
  __shared__ float rs[4], rss[4];
  if (lane == 0){ rs[wid] = s; rss[wid] = ss; }
  __syncthreads();
  float S1 = rs[0]+rs[1]+rs[2]+rs[3];
  float S2 = rss[0]+rss[1]+rss[2]+rss[3];
  float mean = S1 * (1.0f/KD);
  float var  = S2 * (1.0f/KD) - mean*mean;
  float rstd = rsqrtf(var + 1e-5f);
  float4 w4 = ((const float4*)lnw)[tid];
  float4 b4 = ((const float4*)lnb)[tid];
  float y0 = (xv.x - mean)*rstd*w4.x + b4.x;
  float y1 = (xv.y - mean)*rstd*w4.y + b4.y;
  float y2 = (xv.z - mean)*rstd*w4.z + b4.z;
  float y3 = (xv.w - mean)*rstd*w4.w + b4.w;
  float4 yo; yo.x=y0; yo.y=y1; yo.z=y2; yo.w=y3;
  ((float4*)(x1 + (long)t*KD))[tid] = yo;
  ushort4 yb; yb.x=f2bf(y0); yb.y=f2bf(y1); yb.z=f2bf(y2); yb.w=f2bf(y3);
  ((ushort4*)(x1b + (long)t*KD))[tid] = yb;
  // router partials: my 4 dims d0..d0+3
  int d0 = tid*4;
  float rloc[4][8];
#pragma unroll
  for (int c = 0; c < 4; ++c){
    const float4* rp = (const float4*)(rw + (long)(d0 + c)*KE);
    float4 u = rp[0], v2 = rp[1];
    rloc[c][0]=u.x; rloc[c][1]=u.y; rloc[c][2]=u.z; rloc[c][3]=u.w;
    rloc[c][4]=v2.x; rloc[c][5]=v2.y; rloc[c][6]=v2.z; rloc[c][7]=v2.w;
  }
  float yv[4] = {y0,y1,y2,y3};
  float pr[8];
#pragma unroll
  for (int e = 0; e < 8; ++e)
    pr[e] = yv[0]*rloc[0][e] + yv[1]*rloc[1][e] + yv[2]*rloc[2][e] + yv[3]*rloc[3][e];
#pragma unroll
  for (int e = 0; e < 8; ++e)
    for (int off = 32; off; off >>= 1) pr[e] += __shfl_xor(pr[e], off);
  __shared__ float wl[4][8];
  if (lane == 0)
#pragma unroll
    for (int e = 0; e < 8; ++e) wl[wid][e] = pr[e];
  __syncthreads();
  if (tid == 0){
    float lg[8];
#pragma unroll
    for (int e = 0; e < 8; ++e) lg[e] = wl[0][e]+wl[1][e]+wl[2][e]+wl[3][e];
    float mx = lg[0];
    for (int e = 1; e < 8; ++e) mx = fmaxf(mx, lg[e]);
    float pe[8], se = 0.f;
    for (int e = 0; e < 8; ++e){ pe[e] = expf(lg[e]-mx); se += pe[e]; }
    float inv = 1.0f/se;
    for (int e = 0; e < 8; ++e) pe[e] *= inv;
    int e0 = 0;
    for (int e = 1; e < 8; ++e) if (pe[e] > pe[e0]) e0 = e;   // first-index tie break (jax)
    int e1 = (e0 == 0) ? 1 : 0;
    for (int e = 0; e < 8; ++e) if (e != e0 && pe[e] > pe[e1]) e1 = e;
    idx0[t] = e0; idx1[t] = e1;
    gate0[t] = pe[e0]; gate1[t] = pe[e1];
    float lse = mx + logf(se);
    atomicAdd(lse2, lse*lse);
    for (int e = 0; e < 8; ++e) atomicAdd(&psum[e], pe[e]);
  }
}

// ---------------- routing scans ----------------
__launch_bounds__(64)
__global__ void scan1(const int* __restrict__ idx0, const int* __restrict__ idx1,
                      int* __restrict__ rnk0, int* __restrict__ rnk1,
                      int* __restrict__ h0, int* __restrict__ h1){
  int lane = threadIdx.x;
  int t = blockIdx.x*64 + lane;
  int i0 = idx0[t], i1 = idx1[t];
  unsigned long long below = (1ull << lane) - 1ull;
  unsigned long long b0[8], b1[8];
#pragma unroll
  for (int e = 0; e < 8; ++e){
    b0[e] = __ballot(i0 == e);
    b1[e] = __ballot(i1 == e);
  }
  rnk0[t] = __popcll(b0[i0] & below);
  rnk1[t] = __popcll(b1[i1] & below);
  if (lane < 8){
    h0[blockIdx.x*8 + lane] = __popcll(b0[lane]);
    h1[blockIdx.x*8 + lane] = __popcll(b1[lane]);
  }
}

__launch_bounds__(64)
__global__ void scan2(const int* __restrict__ h0, const int* __restrict__ h1,
                      int* __restrict__ bs0, int* __restrict__ bs1, int* __restrict__ cnt0){
  int lane = threadIdx.x;  // lane = chunk id (64 chunks)
  for (int e = 0; e < 8; ++e){
    int v = h0[lane*8 + e];
    int x = v;
    for (int off = 1; off < 64; off <<= 1){
      int y = __shfl_up(x, off);
      if (lane >= off) x += y;
    }
    bs0[lane*8 + e] = x - v;
    int tot = __shfl(x, 63);
    if (lane == 0) cnt0[e] = tot;
    int w = h1[lane*8 + e];
    int xx = w;
    for (int off = 1; off < 64; off <<= 1){
      int y = __shfl_up(xx, off);
      if (lane >= off) xx += y;
    }
    bs1[lane*8 + e] = tot + xx - w;   // slot-1 positions offset by total slot-0 count
  }
}

__global__ void scan3(const int* __restrict__ idx0, const int* __restrict__ idx1,
                      const int* __restrict__ rnk0, const int* __restrict__ rnk1,
                      const int* __restrict__ bs0, const int* __restrict__ bs1,
                      int* __restrict__ dst0, int* __restrict__ dst1, int* __restrict__ slot){
  int t = blockIdx.x*blockDim.x + threadIdx.x;
  if (t >= KN) return;
  int c = t >> 6;
  int e0 = idx0[t], e1 = idx1[t];
  int p0 = bs0[c*8 + e0] + rnk0[t];
  int p1 = bs1[c*8 + e1] + rnk1[t];
  int d0 = (p0 < KCAP) ? (e0*KCAP + p0) : -1;
  int d1 = (p1 < KCAP) ? (e1*KCAP + p1) : -1;
  dst0[t] = d0; dst1[t] = d1;
  if (d0 >= 0) slot[d0] = t;
  if (d1 >= 0) slot[d1] = t;
}

// ---------------- gather xin ----------------
__launch_bounds__(64)
__global__ void gather_xin(const int* __restrict__ slot_token, const u16* __restrict__ x1b,
                           u16* __restrict__ xin){
  long slot = blockIdx.x;
  int t = slot_token[slot];
  uint4* dst = (uint4*)(xin + slot*KD);
  int lane = threadIdx.x;
  if (t >= 0){
    const uint4* src = (const uint4*)(x1b + (long)t*KD);
    dst[lane*2]   = src[lane*2];
    dst[lane*2+1] = src[lane*2+1];
  } else {
    uint4 zz; zz.x = zz.y = zz.z = zz.w = 0;
    dst[lane*2] = zz; dst[lane*2+1] = zz;
  }
}

// ---------------- combine + LN2 -> output ----------------
__launch_bounds__(256)
__global__ void combine_ln2(const float* __restrict__ x1, const u16* __restrict__ oute,
    const int* __restrict__ dest0, const int* __restrict__ dest1,
    const float* __restrict__ gate0, const float* __restrict__ gate1,
    const float* __restrict__ lnw, const float* __restrict__ lnb, float* __restrict__ out){
  const int t = blockIdx.x, tid = threadIdx.x;
  const int lane = tid & 63, wid = tid >> 6;
  float4 xv = ((const float4*)(x1 + (long)t*KD))[tid];
  int d0 = dest0[t], d1 = dest1[t];
  float g0 = gate0[t], g1 = gate1[t];
  if (d0 >= 0){
    ushort4 o = ((const ushort4*)(oute + (long)d0*KD))[tid];
    xv.x += g0*bf2f(o.x); xv.y += g0*bf2f(o.y); xv.z += g0*bf2f(o.z); xv.w += g0*bf2f(o.w);
  }
  if (d1 >= 0){
    ushort4 o = ((const ushort4*)(oute + (long)d1*KD))[tid];
    xv.x += g1*bf2f(o.x); xv.y += g1*bf2f(o.y); xv.z += g1*bf2f(o.z); xv.w += g1*bf2f(o.w);
  }
  float s  = xv.x + xv.y + xv.z + xv.w;
  float ss = xv.x*xv.x + xv.y*xv.y + xv.z*xv.z + xv.w*xv.w;
  for (int off = 32; off; off >>= 1){ s += __shfl_xor(s, off); ss += __shfl_xor(ss, off); }
  __shared__ float rs[4], rss[4];
  if (lane == 0){ rs[wid] = s; rss[wid] = ss; }
  __syncthreads();
  float S1 = rs[0]+rs[1]+rs[2]+rs[3];
  float S2 = rss[0]+rss[1]+rss[2]+rss[3];
  float mean = S1 * (1.0f/KD);
  float var  = S2 * (1.0f/KD) - mean*mean;
  float rstd = rsqrtf(var + 1e-5f);
  float4 w4 = ((const float4*)lnw)[tid];
  float4 b4 = ((const float4*)lnb)[tid];
  float4 yo;
  yo.x = (xv.x - mean)*rstd*w4.x + b4.x;
  yo.y = (xv.y - mean)*rstd*w4.y + b4.y;
  yo.z = (xv.z - mean)*rstd*w4.z + b4.z;
  yo.w = (xv.w - mean)*rstd*w4.w + b4.w;
  ((float4*)(out + (long)t*KD))[tid] = yo;
}

// ---------------- aux scalar ----------------
__global__ void aux_k(const int* __restrict__ cnt0, const float* __restrict__ psum,
                      const float* __restrict__ lse2, float* __restrict__ out){
  if (threadIdx.x == 0 && blockIdx.x == 0){
    float bal = 0.f;
    for (int e = 0; e < 8; ++e)
      bal += ((float)cnt0[e] * (1.0f/KN)) * (psum[e] * (1.0f/KN));
    bal *= (float)KE;
    float zl = lse2[0] * (1.0f/KN);
    out[(long)KN*KD] = 0.01f*bal + 0.001f*zl;
  }
}

// ---------------- host ----------------
extern "C" void kernel_launch(void* const* d_in, const int* in_sizes, int n_in,
                              void* d_out, int out_size, void* d_ws, size_t ws_size,
                              hipStream_t stream){
  const float* q    = (const float*)d_in[0];
  const float* k    = (const float*)d_in[1];
  const float* v    = (const float*)d_in[2];
  const float* inw  = (const float*)d_in[3];
  const float* inb  = (const float*)d_in[4];
  const float* outw = (const float*)d_in[5];
  const float* outb = (const float*)d_in[6];
  const float* ln1w = (const float*)d_in[7];
  const float* ln1b = (const float*)d_in[8];
  const float* ln2w = (const float*)d_in[9];
  const float* ln2b = (const float*)d_in[10];
  const float* rw   = (const float*)d_in[11];
  const float* w1   = (const float*)d_in[12];
  const float* b1   = (const float*)d_in[13];
  const float* w2   = (const float*)d_in[14];
  const float* b2   = (const float*)d_in[15];
  float* out = (float*)d_out;
  char* ws = (char*)d_ws;

  constexpr size_t PLB  = (size_t)KN*KD*2;            // 8,388,608 plane bytes
  constexpr size_t oW1T = 0;
  constexpr size_t oW2T = oW1T + 67108864;
  constexpr size_t oWQh = oW2T + 67108864;
  constexpr size_t oWQm = oWQh + 6291456;
  constexpr size_t oWQl = oWQm + 6291456;
  constexpr size_t oWOh = oWQl + 6291456;
  constexpr size_t oWOm = oWOh + 2097152;
  constexpr size_t oWOl = oWOm + 2097152;
  constexpr size_t oX1  = oWOl + 2097152;
  constexpr size_t oX1B = oX1  + 16777216;
  constexpr size_t oMISC= oX1B + 8388608;
  constexpr size_t oU1  = oMISC + 1048576;   // q/k/v splits -> attnproj+o3 -> h
  constexpr size_t oU2  = oU1 + 83886080;    // qh/kh/vt -> xin + out_e
  constexpr size_t oU3  = oU2 + 75497472;    // scoresF + P planes (chunked)
  constexpr size_t oEND = oU3 + 41943040;    // ~369 MiB
  if (ws_size < oEND) return;

  u16* W1T = (u16*)(ws + oW1T);
  u16* W2T = (u16*)(ws + oW2T);
  u16* WQh = (u16*)(ws + oWQh); u16* WQm = (u16*)(ws + oWQm); u16* WQl = (u16*)(ws + oWQl);
  u16* WOh = (u16*)(ws + oWOh); u16* WOm = (u16*)(ws + oWOm); u16* WOl = (u16*)(ws + oWOl);
  float* X1 = (float*)(ws + oX1);
  u16* X1B  = (u16*)(ws + oX1B);

  int*   IDX0 = (int*)(ws + oMISC);
  int*   IDX1 = (int*)(ws + oMISC + 16384);
  int*   RNK0 = (int*)(ws + oMISC + 32768);
  int*   RNK1 = (int*)(ws + oMISC + 49152);
  int*   DST0 = (int*)(ws + oMISC + 65536);
  int*   DST1 = (int*)(ws + oMISC + 81920);
  float* G0   = (float*)(ws + oMISC + 98304);
  float* G1   = (float*)(ws + oMISC + 114688);
  int*   H0   = (int*)(ws + oMISC + 131072);
  int*   H1   = (int*)(ws + oMISC + 133120);
  int*   BS0  = (int*)(ws + oMISC + 135168);
  int*   BS1  = (int*)(ws + oMISC + 137216);
  int*   CNT0 = (int*)(ws + oMISC + 139264);
  float* PSUM = (float*)(ws + oMISC + 139296);
  float* LSE2 = (float*)(ws + oMISC + 139328);
  int*   SLOT = (int*)(ws + oMISC + 139776);

  u16* Qs0 = (u16*)(ws + oU1);           u16* Qs1 = (u16*)(ws + oU1 + PLB);   u16* Qs2 = (u16*)(ws + oU1 + 2*PLB);
  u16* Ks0 = (u16*)(ws + oU1 + 3*PLB);   u16* Ks1 = (u16*)(ws + oU1 + 4*PLB); u16* Ks2 = (u16*)(ws + oU1 + 5*PLB);
  u16* Vs0 = (u16*)(ws + oU1 + 6*PLB);   u16* Vs1 = (u16*)(ws + oU1 + 7*PLB); u16* Vs2 = (u16*)(ws + oU1 + 8*PLB);
  float* ATTN = (float*)(ws + oU1);                          // reuse after splits die
  u16* O30 = (u16*)(ws + oU1 + 16777216);
  u16* O31 = (u16*)(ws + oU1 + 16777216 + PLB);
  u16* O32 = (u16*)(ws + oU1 + 16777216 + 2*PLB);
  u16* HBUF = (u16*)(ws + oU1);                              // reuse for FFN h

  u16* QH0 = (u16*)(ws + oU2);           u16* QH1 = (u16*)(ws + oU2 + PLB);   u16* QH2 = (u16*)(ws + oU2 + 2*PLB);
  u16* KH0 = (u16*)(ws + oU2 + 3*PLB);   u16* KH1 = (u16*)(ws + oU2 + 4*PLB); u16* KH2 = (u16*)(ws + oU2 + 5*PLB);
  u16* VT0 = (u16*)(ws + oU2 + 6*PLB);   u16* VT1 = (u16*)(ws + oU2 + 7*PLB); u16* VT2 = (u16*)(ws + oU2 + 8*PLB);
  u16* XIN  = (u16*)(ws + oU2);                              // reuse after attention
  u16* OUTE = (u16*)(ws + oU2 + 20971520);

  float* SCF = (float*)(ws + oU3);
  u16* PH  = (u16*)(ws + oU3 + 16777216);
  u16* PM  = (u16*)(ws + oU3 + 16777216 + PLB);
  u16* PLo = (u16*)(ws + oU3 + 16777216 + 2*PLB);

  // init accumulators / slot map
  hipMemsetAsync(ws + oMISC + 139264, 0, 128, stream);
  hipMemsetAsync(ws + oMISC + 139776, 0xFF, (size_t)KE*KCAP*4, stream);

  // splits (3-plane bf16)
  split3k<<<4096, 256, 0, stream>>>(q, Qs0, Qs1, Qs2, (long)KN*KD/4);
  split3k<<<4096, 256, 0, stream>>>(k, Ks0, Ks1, Ks2, (long)KN*KD/4);
  split3k<<<4096, 256, 0, stream>>>(v, Vs0, Vs1, Vs2, (long)KN*KD/4);
  split3k<<<3072, 256, 0, stream>>>(inw, WQh, WQm, WQl, 786432);
  split3k<<<1024, 256, 0, stream>>>(outw, WOh, WOm, WOl, 262144);

  // weight transposes to (N,K) bf16 for NT GEMM
  trans_b<<<dim3(KDFF/32, KD/32, KE), dim3(32,8), 0, stream>>>(w1, W1T, KD, KDFF);
  trans_b<<<dim3(KD/32, KDFF/32, KE), dim3(32,8), 0, stream>>>(w2, W2T, KDFF, KD);

  // QKV projections (b3x6) -> head layouts
  GArgs ga{};
  ga.lda = KD; ga.sA = 0; ga.ldb = KD; ga.sB = 0;
  ga.K = KD; ga.chunkBase = 0; ga.scale = 1.f; ga.biasStride = 0; ga.outF = nullptr;
  ga.Ah=Qs0; ga.Am=Qs1; ga.Al=Qs2; ga.Bh=WQh; ga.Bm=WQm; ga.Bl=WQl;
  ga.bias=inb; ga.mode=0; ga.o0=QH0; ga.o1=QH1; ga.o2=QH2;
  gemm_nt<true><<<dim3(16,64,1), 64, 0, stream>>>(ga);
  ga.Ah=Ks0; ga.Am=Ks1; ga.Al=Ks2; ga.Bh=WQh+1048576; ga.Bm=WQm+1048576; ga.Bl=WQl+1048576;
  ga.bias=inb+1024; ga.mode=0; ga.o0=KH0; ga.o1=KH1; ga.o2=KH2;
  gemm_nt<true><<<dim3(16,64,1), 64, 0, stream>>>(ga);
  ga.Ah=Vs0; ga.Am=Vs1; ga.Al=Vs2; ga.Bh=WQh+2097152; ga.Bm=WQm+2097152; ga.Bl=WQl+2097152;
  ga.bias=inb+2048; ga.mode=1; ga.o0=VT0; ga.o1=VT1; ga.o2=VT2;
  gemm_nt<true><<<dim3(16,64,1), 64, 0, stream>>>(ga);

  // attention, chunked over bh
  for (int c = 0; c < KNCH; ++c){
    long hoff = (long)c * KCHB * KS * KDH;   // same element offset for head planes and vt planes
    GArgs gs{};
    gs.Ah=QH0+hoff; gs.Am=QH1+hoff; gs.Al=QH2+hoff; gs.lda=KDH; gs.sA=(long)KS*KDH;
    gs.Bh=KH0+hoff; gs.Bm=KH1+hoff; gs.Bl=KH2+hoff; gs.ldb=KDH; gs.sB=(long)KS*KDH;
    gs.bias=nullptr; gs.biasStride=0; gs.outF=SCF; gs.o0=gs.o1=gs.o2=nullptr;
    gs.K=KDH; gs.mode=2; gs.chunkBase=0; gs.scale=0.125f;
    gemm_nt<true><<<dim3(8,8,KCHB), 64, 0, stream>>>(gs);

    softmax3<<<KCHB*KS, 64, 0, stream>>>(SCF, PH, PM, PLo);

    GArgs gp{};
    gp.Ah=PH; gp.Am=PM; gp.Al=PLo; gp.lda=KS; gp.sA=(long)KS*KS;
    gp.Bh=VT0+hoff; gp.Bm=VT1+hoff; gp.Bl=VT2+hoff; gp.ldb=KS; gp.sB=(long)KDH*KS;
    gp.bias=nullptr; gp.biasStride=0; gp.outF=nullptr;
    gp.o0=O30; gp.o1=O31; gp.o2=O32;
    gp.K=KS; gp.mode=3; gp.chunkBase=c*KCHB; gp.scale=1.f;
    gemm_nt<true><<<dim3(1,8,KCHB), 64, 0, stream>>>(gp);
  }

  // out-projection (b3x6) -> attnproj fp32
  GArgs go{};
  go.Ah=O30; go.Am=O31; go.Al=O32; go.lda=KD; go.sA=0;
  go.Bh=WOh; go.Bm=WOm; go.Bl=WOl; go.ldb=KD; go.sB=0;
  go.bias=outb; go.biasStride=0; go.outF=ATTN; go.o0=go.o1=go.o2=nullptr;
  go.K=KD; go.mode=4; go.chunkBase=0; go.scale=1.f;
  gemm_nt<true><<<dim3(16,64,1), 64, 0, stream>>>(go);

  // LN1 + router
  ln1_router<<<KN, 256, 0, stream>>>(q, ATTN, ln1w, ln1b, rw, X1, X1B,
                                     IDX0, IDX1, G0, G1, PSUM, LSE2);
  // capacity-ordered routing
  scan1<<<64, 64, 0, stream>>>(IDX0, IDX1, RNK0, RNK1, H0, H1);
  scan2<<<1, 64, 0, stream>>>(H0, H1, BS0, BS1, CNT0);
  scan3<<<16, 256, 0, stream>>>(IDX0, IDX1, RNK0, RNK1, BS0, BS1, DST0, DST1, SLOT);
  gather_xin<<<KE*KCAP, 64, 0, stream>>>(SLOT, X1B, XIN);

  // expert FFN (plain bf16)
  GArgs f1{};
  f1.Ah=XIN; f1.Am=nullptr; f1.Al=nullptr; f1.lda=KD; f1.sA=(long)KCAP*KD;
  f1.Bh=W1T; f1.Bm=nullptr; f1.Bl=nullptr; f1.ldb=KD; f1.sB=(long)KDFF*KD;
  f1.bias=b1; f1.biasStride=KDFF; f1.outF=nullptr; f1.o0=HBUF; f1.o1=f1.o2=nullptr;
  f1.K=KD; f1.mode=5; f1.chunkBase=0; f1.scale=1.f;
  gemm_nt<false><<<dim3(64,20,8), 64, 0, stream>>>(f1);

  GArgs f2{};
  f2.Ah=HBUF; f2.Am=nullptr; f2.Al=nullptr; f2.lda=KDFF; f2.sA=(long)KCAP*KDFF;
  f2.Bh=W2T; f2.Bm=nullptr; f2.Bl=nullptr; f2.ldb=KDFF; f2.sB=(long)KD*KDFF;
  f2.bias=b2; f2.biasStride=KD; f2.outF=nullptr; f2.o0=OUTE; f2.o1=f2.o2=nullptr;
  f2.K=KDFF; f2.mode=6; f2.chunkBase=0; f2.scale=1.f;
  gemm_nt<false><<<dim3(16,20,8), 64, 0, stream>>>(f2);

  // combine + LN2 -> output, plus aux
  combine_ln2<<<KN, 256, 0, stream>>>(X1, OUTE, DST0, DST1, G0, G1, ln2w, ln2b, out);
  aux_k<<<1, 64, 0, stream>>>(CNT0, PSUM, LSE2, out);
}

// Round 2
// 1634.783 us; speedup vs baseline: 1.6135x; 1.6135x over previous
//
#include <hip/hip_runtime.h>
#include <cstdint>
#include <cstddef>

// ---------------- constants ----------------
#define KB   8
#define KS   512
#define KD   1024
#define KH   16
#define KDH  64
#define KE   8
#define KDFF 4096
#define KN   4096      // B*S tokens
#define KCAP 1280      // ceil(2*4096/8*1.25)
#define KCHB 16        // attention bh per chunk
#define KNCH 8         // 128 / KCHB

typedef unsigned short u16;
typedef __bf16 bf16x8 __attribute__((ext_vector_type(8)));
typedef float  f32x4  __attribute__((ext_vector_type(4)));

__device__ __forceinline__ u16 f2bf(float f){
  unsigned u = __builtin_bit_cast(unsigned, f);
  u = (u + 0x7FFFu + ((u >> 16) & 1u)) >> 16;   // RNE
  return (u16)u;
}
__device__ __forceinline__ float bf2f(u16 h){
  unsigned u = ((unsigned)h) << 16;
  return __builtin_bit_cast(float, u);
}
__device__ __forceinline__ void split3v(float f, unsigned short &a, unsigned short &b, unsigned short &c){
  a = f2bf(f);
  float r = f - bf2f(a);
  b = f2bf(r);
  c = f2bf(r - bf2f(b));
}
__device__ __forceinline__ bf16x8 ld8(const u16* p){
  uint4 v = *(const uint4*)p;
  return __builtin_bit_cast(bf16x8, v);
}
// async global->LDS, 16B per lane; lds ptr must be wave-uniform (HW adds lane*16)
__device__ __forceinline__ void async16(const u16* g, u16* l){
  __builtin_amdgcn_global_load_lds(
      (const __attribute__((address_space(1))) unsigned int*)(g),
      (__attribute__((address_space(3))) unsigned int*)(l),
      16, 0, 0);
}

struct GArgs {
  const u16 *Ah, *Am, *Al;
  const u16 *Bh, *Bm, *Bl;
  long lda, sA, ldb, sB;         // element strides
  const float* bias; long biasStride;
  float* outF;
  u16 *o0, *o1, *o2;
  int K, mode, chunkBase;
  float scale;
};

// ---------------- legacy 1-wave GEMM (kept for PV: N=64) ----------------
template<bool S3>
__launch_bounds__(64)
__global__ void gemm_nt(GArgs g){
  const int lane = threadIdx.x;
  const int quad = lane >> 4;
  const int r    = lane & 15;
  const int z    = blockIdx.z;
  const long m0  = (long)blockIdx.y * 64;
  const long n0  = (long)blockIdx.x * 64;
  const u16* Ah = g.Ah + (long)z * g.sA;
  const u16* Bh = g.Bh + (long)z * g.sB;
  const u16* Am = S3 ? (g.Am + (long)z * g.sA) : nullptr;
  const u16* Al = S3 ? (g.Al + (long)z * g.sA) : nullptr;
  const u16* Bm = S3 ? (g.Bm + (long)z * g.sB) : nullptr;
  const u16* Bl = S3 ? (g.Bl + (long)z * g.sB) : nullptr;
  f32x4 acc[4][4] = {};
  const long ko = quad * 8;
  for (int kt = 0; kt < g.K; kt += 32){
    bf16x8 a0[4], a1[4], a2[4], c0[4], c1[4], c2[4];
#pragma unroll
    for (int i = 0; i < 4; ++i){
      long row = m0 + i*16 + r;
      a0[i] = ld8(Ah + row*g.lda + kt + ko);
      if (S3){
        a1[i] = ld8(Am + row*g.lda + kt + ko);
        a2[i] = ld8(Al + row*g.lda + kt + ko);
      }
    }
#pragma unroll
    for (int j = 0; j < 4; ++j){
      long col = n0 + j*16 + r;
      c0[j] = ld8(Bh + col*g.ldb + kt + ko);
      if (S3){
        c1[j] = ld8(Bm + col*g.ldb + kt + ko);
        c2[j] = ld8(Bl + col*g.ldb + kt + ko);
      }
    }
#pragma unroll
    for (int i = 0; i < 4; ++i)
#pragma unroll
      for (int j = 0; j < 4; ++j){
        acc[i][j] = __builtin_amdgcn_mfma_f32_16x16x32_bf16(a0[i], c0[j], acc[i][j], 0, 0, 0);
        if (S3){
          acc[i][j] = __builtin_amdgcn_mfma_f32_16x16x32_bf16(a0[i], c1[j], acc[i][j], 0, 0, 0);
          acc[i][j] = __builtin_amdgcn_mfma_f32_16x16x32_bf16(a1[i], c0[j], acc[i][j], 0, 0, 0);
          acc[i][j] = __builtin_amdgcn_mfma_f32_16x16x32_bf16(a0[i], c2[j], acc[i][j], 0, 0, 0);
          acc[i][j] = __builtin_amdgcn_mfma_f32_16x16x32_bf16(a2[i], c0[j], acc[i][j], 0, 0, 0);
          acc[i][j] = __builtin_amdgcn_mfma_f32_16x16x32_bf16(a1[i], c1[j], acc[i][j], 0, 0, 0);
        }
      }
  }
#pragma unroll
  for (int i = 0; i < 4; ++i){
#pragma unroll
    for (int rr = 0; rr < 4; ++rr){
      long row = m0 + i*16 + quad*4 + rr;
#pragma unroll
      for (int j = 0; j < 4; ++j){
        long col = n0 + j*16 + r;
        float v = acc[i][j][rr];
        if (g.mode == 3){         // PV out -> (B,S,D), 3-plane split
          int bh = g.chunkBase + z;
          long b = bh >> 4, h = bh & 15;
          long idx = (b*KS + row)*KD + h*KDH + col;
          unsigned short x, y, w; split3v(v, x, y, w);
          g.o0[idx] = x; g.o1[idx] = y; g.o2[idx] = w;
        }
      }
    }
  }
}

// ---------------- m97-style 128x128 4-wave GEMM, LDS staged via global_load_lds ----
// LDS layout per plane: 128 rows x 32 cols bf16 (64B rows), chunk slot XOR swizzle:
// global chunk c of row stored at slot (c ^ ((row>>1)&3)) -> 2-way max bank conflict.
template<bool S3>
__launch_bounds__(256)
__global__ void gemm128(GArgs g){
  constexpr int NP = S3 ? 3 : 1;
  __shared__ __align__(16) u16 sm[NP*2*4096];
  const int tid  = threadIdx.x;
  const int lane = tid & 63;
  const int wave = tid >> 6;
  const int quad = lane >> 4;
  const int r    = lane & 15;
  const int wm = (wave & 1) * 64;
  const int wn = (wave >> 1) * 64;
  const int z  = blockIdx.z;
  const long m0 = (long)blockIdx.y * 128;
  const long n0 = (long)blockIdx.x * 128;
  const u16* Ap[NP]; const u16* Bp[NP];
  Ap[0] = g.Ah + (long)z*g.sA; Bp[0] = g.Bh + (long)z*g.sB;
  if (S3){
    Ap[1] = g.Am + (long)z*g.sA; Ap[2] = g.Al + (long)z*g.sA;
    Bp[1] = g.Bm + (long)z*g.sB; Bp[2] = g.Bl + (long)z*g.sB;
  }
  const int srow   = tid >> 2;                       // 0..63
  const int schunk = (tid & 3) ^ ((tid >> 3) & 3);   // swizzled source chunk
  f32x4 acc[4][4] = {};
  for (int kt = 0; kt < g.K; kt += 32){
    // ---- stage A/B tiles (each plane 8KB = 2 rounds of 256 threads x 16B) ----
#pragma unroll
    for (int p = 0; p < NP; ++p){
#pragma unroll
      for (int r0 = 0; r0 < 2; ++r0){
        long row = r0*64 + srow;
        u16* lA = &sm[p*4096       + r0*2048 + wave*512];
        u16* lB = &sm[(NP+p)*4096  + r0*2048 + wave*512];
        async16(Ap[p] + (m0 + row)*g.lda + kt + schunk*8, lA);
        async16(Bp[p] + (n0 + row)*g.ldb + kt + schunk*8, lB);
      }
    }
    __syncthreads();
    // ---- fragments from LDS ----
    bf16x8 af[NP][4], bf[NP][4];
#pragma unroll
    for (int i = 0; i < 4; ++i){
      int row = wm + i*16 + r;
      int slot = quad ^ ((row >> 1) & 3);
#pragma unroll
      for (int p = 0; p < NP; ++p)
        af[p][i] = ld8(&sm[p*4096 + row*32 + slot*8]);
    }
#pragma unroll
    for (int j = 0; j < 4; ++j){
      int row = wn + j*16 + r;
      int slot = quad ^ ((row >> 1) & 3);
#pragma unroll
      for (int p = 0; p < NP; ++p)
        bf[p][j] = ld8(&sm[(NP+p)*4096 + row*32 + slot*8]);
    }
#pragma unroll
    for (int i = 0; i < 4; ++i)
#pragma unroll
      for (int j = 0; j < 4; ++j){
        acc[i][j] = __builtin_amdgcn_mfma_f32_16x16x32_bf16(af[0][i], bf[0][j], acc[i][j], 0, 0, 0);
        if (S3){
          acc[i][j] = __builtin_amdgcn_mfma_f32_16x16x32_bf16(af[0][i], bf[1][j], acc[i][j], 0, 0, 0);
          acc[i][j] = __builtin_amdgcn_mfma_f32_16x16x32_bf16(af[1][i], bf[0][j], acc[i][j], 0, 0, 0);
          acc[i][j] = __builtin_amdgcn_mfma_f32_16x16x32_bf16(af[0][i], bf[2][j], acc[i][j], 0, 0, 0);
          acc[i][j] = __builtin_amdgcn_mfma_f32_16x16x32_bf16(af[2][i], bf[0][j], acc[i][j], 0, 0, 0);
          acc[i][j] = __builtin_amdgcn_mfma_f32_16x16x32_bf16(af[1][i], bf[1][j], acc[i][j], 0, 0, 0);
        }
      }
    __syncthreads();
  }
  // ---- epilogue: C/D layout col=lane&15, row=quad*4+reg ----
#pragma unroll
  for (int i = 0; i < 4; ++i){
#pragma unroll
    for (int rr = 0; rr < 4; ++rr){
      long row = m0 + wm + i*16 + quad*4 + rr;
#pragma unroll
      for (int j = 0; j < 4; ++j){
        long col = n0 + wn + j*16 + r;
        float v = acc[i][j][rr];
        switch (g.mode){
          case 2: {               // scores (scaled, fp32)
            g.outF[((long)z*KS + row)*KS + col] = v * g.scale;
            break;
          }
          case 4: {               // out-proj: +bias, fp32 linear
            v += g.bias[col];
            g.outF[row*KD + col] = v;
            break;
          }
          case 5: {               // FFN1: +b1, gelu(tanh approx), bf16
            v += g.bias[(long)z*g.biasStride + col];
            float u = v + 0.044715f*v*v*v;
            v = 0.5f*v*(1.0f + tanhf(0.7978845608028654f*u));
            g.o0[((long)z*KCAP + row)*KDFF + col] = f2bf(v);
            break;
          }
          case 6: {               // FFN2: +b2, bf16
            v += g.bias[(long)z*g.biasStride + col];
            g.o0[((long)z*KCAP + row)*KD + col] = f2bf(v);
            break;
          }
          default: {              // mode 7: fused QKV -> head layout, 3-plane split
            v += g.bias[(long)z*g.biasStride + col];
            long b = row >> 9, s = row & 511;
            long h = col >> 6, d = col & 63;
            long idx = (z < 2) ? (((b*KH + h)*KS + s)*KDH + d)    // Q,K: (B,H,S,dh)
                               : (((b*KH + h)*KDH + d)*KS + s);   // V:   (B,H,dh,S)
            u16* d0 = g.o0 + (long)z * 3 * ((long)KN*KD);
            u16* d1 = d0 + (long)KN*KD;
            u16* d2 = d1 + (long)KN*KD;
            unsigned short x, y, w; split3v(v, x, y, w);
            d0[idx] = x; d1[idx] = y; d2[idx] = w;
            break;
          }
        }
      }
    }
  }
}

// ---------------- prep kernels ----------------
__global__ void split3k(const float* __restrict__ x, u16* __restrict__ h, u16* __restrict__ m,
                        u16* __restrict__ l, long n4){
  long i = (long)blockIdx.x*blockDim.x + threadIdx.x;
  if (i >= n4) return;
  float4 v = ((const float4*)x)[i];
  ushort4 a, b, c;
  split3v(v.x, a.x, b.x, c.x);
  split3v(v.y, a.y, b.y, c.y);
  split3v(v.z, a.z, b.z, c.z);
  split3v(v.w, a.w, b.w, c.w);
  ((ushort4*)h)[i] = a; ((ushort4*)m)[i] = b; ((ushort4*)l)[i] = c;
}

// batched transpose: in (z,R,C) f32 -> out (z,C,R) bf16
__global__ void trans_b(const float* __restrict__ in, u16* __restrict__ outp, int R, int Cc){
  __shared__ float tile[32][33];
  long z = blockIdx.z;
  const float* ip = in + z*(long)R*Cc;
  u16* op = outp + z*(long)R*Cc;
  int c0 = blockIdx.x*32, r0 = blockIdx.y*32;
  int tx = threadIdx.x, ty = threadIdx.y;
  for (int rr = ty; rr < 32; rr += 8)
    tile[rr][tx] = ip[(long)(r0+rr)*Cc + c0 + tx];
  __syncthreads();
  for (int cc = ty; cc < 32; cc += 8)
    op[(long)(c0+cc)*R + r0 + tx] = f2bf(tile[tx][cc]);
}

// ---------------- softmax over 512-wide rows -> 3-plane bf16 P ----------------
__launch_bounds__(64)
__global__ void softmax3(const float* __restrict__ scores, u16* __restrict__ ph,
                         u16* __restrict__ pm, u16* __restrict__ pl){
  long row = blockIdx.x;
  const float* rp = scores + row * KS;
  int lane = threadIdx.x;
  float4 a = ((const float4*)rp)[lane*2];
  float4 b = ((const float4*)rp)[lane*2 + 1];
  float vv[8] = {a.x,a.y,a.z,a.w,b.x,b.y,b.z,b.w};
  float m = vv[0];
#pragma unroll
  for (int t = 1; t < 8; ++t) m = fmaxf(m, vv[t]);
  for (int off = 32; off; off >>= 1) m = fmaxf(m, __shfl_xor(m, off));
  float s = 0.f;
#pragma unroll
  for (int t = 0; t < 8; ++t){ vv[t] = expf(vv[t] - m); s += vv[t]; }
  for (int off = 32; off; off >>= 1) s += __shfl_xor(s, off);
  float inv = 1.0f / s;
  unsigned short hh[8], mm[8], ll[8];
#pragma unroll
  for (int t = 0; t < 8; ++t){
    float p = vv[t] * inv;
    split3v(p, hh[t], mm[t], ll[t]);
  }
  ushort4* dh = (ushort4*)(ph + row*KS + lane*8);
  dh[0] = make_ushort4(hh[0],hh[1],hh[2],hh[3]);
  dh[1] = make_ushort4(hh[4],hh[5],hh[6],hh[7]);
  ushort4* dm = (ushort4*)(pm + row*KS + lane*8);
  dm[0] = make_ushort4(mm[0],mm[1],mm[2],mm[3]);
  dm[1] = make_ushort4(mm[4],mm[5],mm[6],mm[7]);
  ushort4* dl = (ushort4*)(pl + row*KS + lane*8);
  dl[0] = make_ushort4(ll[0],ll[1],ll[2],ll[3]);
  dl[1] = make_ushort4(ll[4],ll[5],ll[6],ll[7]);
}

// ---------------- LN1 + router (fp32 exact; NO contended atomics) ----------------
__launch_bounds__(256)
__global__ void ln1_router(const float* __restrict__ q, const float* __restrict__ attn,
    const float* __restrict__ lnw, const float* __restrict__ lnb, const float* __restrict__ rw,
    float* __restrict__ x1, u16* __restrict__ x1b,
    int* __restrict__ idx0, int* __restrict__ idx1, float* __restrict__ gate0, float* __restrict__ gate1,
    float* __restrict__ ptok, float* __restrict__ lset){
  const int t = blockIdx.x, tid = threadIdx.x;
  const int lane = tid & 63, wid = tid >> 6;
  float4 xv = ((const float4*)(q    + (long)t*KD))[tid];
  float4 av = ((const float4*)(attn + (long)t*KD))[tid];
  xv.x += av.x; xv.y += av.y; xv.z += av.z; xv.w += av.w;
  float s  = xv.x + xv.y + xv.z + xv.w;
  float ss = xv.x*xv.x + xv.y*xv.y + xv.z*xv.z + xv.w*xv.w;
  for (int off = 32; off; off >>= 1){ s += __shfl_xor(s, off); ss += __shfl_xor(ss, off); }
  __shared__ float rs[4], rss[4];
  if (lane == 0){ rs[wid] = s; rss[wid] = ss; }
  __syncthreads();
  float S1 = rs[0]+rs[1]+rs[2]+rs[3];
  float S2 = rss[0]+rss[1]+rss[2]+rss[3];
  float mean = S1 * (1.0f/KD);
  float var  = S2 * (1.0f/KD) - mean*mean;
  float rstd = rsqrtf(var + 1e-5f);
  float4 w4 = ((const float4*)lnw)[tid];
  float4 b4 = ((const float4*)lnb)[tid];
  float y0 = (xv.x - mean)*rstd*w4.x + b4.x;
  float y1 = (xv.y - mean)*rstd*w4.y + b4.y;
  float y2 = (xv.z - mean)*rstd*w4.z + b4.z;
  float y3 = (xv.w - mean)*rstd*w4.w + b4.w;
  float4 yo; yo.x=y0; yo.y=y1; yo.z=y2; yo.w=y3;
  ((float4*)(x1 + (long)t*KD))[tid] = yo;
  ushort4 yb; yb.x=f2bf(y0); yb.y=f2bf(y1); yb.z=f2bf(y2); yb.w=f2bf(y3);
  ((ushort4*)(x1b + (long)t*KD))[tid] = yb;
  int d0 = tid*4;
  float rloc[4][8];
#pragma unroll
  for (int c = 0; c < 4; ++c){
    const float4* rp = (const float4*)(rw + (long)(d0 + c)*KE);
    float4 u = rp[0], v2 = rp[1];
    rloc[c][0]=u.x; rloc[c][1]=u.y; rloc[c][2]=u.z; rloc[c][3]=u.w;
    rloc[c][4]=v2.x; rloc[c][5]=v2.y; rloc[c][6]=v2.z; rloc[c][7]=v2.w;
  }
  float yv[4] = {y0,y1,y2,y3};
  float pr[8];
#pragma unroll
  for (int e = 0; e < 8; ++e)
    pr[e] = yv[0]*rloc[0][e] + yv[1]*rloc[1][e] + yv[2]*rloc[2][e] + yv[3]*rloc[3][e];
#pragma unroll
  for (int e = 0; e < 8; ++e)
    for (int off = 32; off; off >>= 1) pr[e] += __shfl_xor(pr[e], off);
  __shared__ float wl[4][8];
  if (lane == 0)
#pragma unroll
    for (int e = 0; e < 8; ++e) wl[wid][e] = pr[e];
  __syncthreads();
  if (tid == 0){
    float lg[8];
#pragma unroll
    for (int e = 0; e < 8; ++e) lg[e] = wl[0][e]+wl[1][e]+wl[2][e]+wl[3][e];
    float mx = lg[0];
    for (int e = 1; e < 8; ++e) mx = fmaxf(mx, lg[e]);
    float pe[8], se = 0.f;
    for (int e = 0; e < 8; ++e){ pe[e] = expf(lg[e]-mx); se += pe[e]; }
    float inv = 1.0f/se;
    for (int e = 0; e < 8; ++e) pe[e] *= inv;
    int e0 = 0;
    for (int e = 1; e < 8; ++e) if (pe[e] > pe[e0]) e0 = e;   // first-index tie break (jax)
    int e1 = (e0 == 0) ? 1 : 0;
    for (int e = 0; e < 8; ++e) if (e != e0 && pe[e] > pe[e1]) e1 = e;
    idx0[t] = e0; idx1[t] = e1;
    gate0[t] = pe[e0]; gate1[t] = pe[e1];
    for (int e = 0; e < 8; ++e) ptok[(long)t*8 + e] = pe[e];
    lset[t] = mx + logf(se);
  }
}

// ---------------- routing scans ----------------
__launch_bounds__(64)
__global__ void scan1(const int* __restrict__ idx0, const int* __restrict__ idx1,
                      int* __restrict__ rnk0, int* __restrict__ rnk1,
                      int* __restrict__ h0, int* __restrict__ h1){
  int lane = threadIdx.x;
  int t = blockIdx.x*64 + lane;
  int i0 = idx0[t], i1 = idx1[t];
  unsigned long long below = (1ull << lane) - 1ull;
  unsigned long long b0[8], b1[8];
#pragma unroll
  for (int e = 0; e < 8; ++e){
    b0[e] = __ballot(i0 == e);
    b1[e] = __ballot(i1 == e);
  }
  rnk0[t] = __popcll(b0[i0] & below);
  rnk1[t] = __popcll(b1[i1] & below);
  if (lane < 8){
    h0[blockIdx.x*8 + lane] = __popcll(b0[lane]);
    h1[blockIdx.x*8 + lane] = __popcll(b1[lane]);
  }
}

__launch_bounds__(64)
__global__ void scan2(const int* __restrict__ h0, const int* __restrict__ h1,
                      int* __restrict__ bs0, int* __restrict__ bs1, int* __restrict__ cnt0){
  int lane = threadIdx.x;  // lane = chunk id (64 chunks)
  for (int e = 0; e < 8; ++e){
    int v = h0[lane*8 + e];
    int x = v;
    for (int off = 1; off < 64; off <<= 1){
      int y = __shfl_up(x, off);
      if (lane >= off) x += y;
    }
    bs0[lane*8 + e] = x - v;
    int tot = __shfl(x, 63);
    if (lane == 0) cnt0[e] = tot;
    int w = h1[lane*8 + e];
    int xx = w;
    for (int off = 1; off < 64; off <<= 1){
      int y = __shfl_up(xx, off);
      if (lane >= off) xx += y;
    }
    bs1[lane*8 + e] = tot + xx - w;
  }
}

__global__ void scan3(const int* __restrict__ idx0, const int* __restrict__ idx1,
                      const int* __restrict__ rnk0, const int* __restrict__ rnk1,
                      const int* __restrict__ bs0, const int* __restrict__ bs1,
                      int* __restrict__ dst0, int* __restrict__ dst1, int* __restrict__ slot){
  int t = blockIdx.x*blockDim.x + threadIdx.x;
  if (t >= KN) return;
  int c = t >> 6;
  int e0 = idx0[t], e1 = idx1[t];
  int p0 = bs0[c*8 + e0] + rnk0[t];
  int p1 = bs1[c*8 + e1] + rnk1[t];
  int d0 = (p0 < KCAP) ? (e0*KCAP + p0) : -1;
  int d1 = (p1 < KCAP) ? (e1*KCAP + p1) : -1;
  dst0[t] = d0; dst1[t] = d1;
  if (d0 >= 0) slot[d0] = t;
  if (d1 >= 0) slot[d1] = t;
}

// ---------------- gather xin ----------------
__launch_bounds__(64)
__global__ void gather_xin(const int* __restrict__ slot_token, const u16* __restrict__ x1b,
                           u16* __restrict__ xin){
  long slot = blockIdx.x;
  int t = slot_token[slot];
  uint4* dst = (uint4*)(xin + slot*KD);
  int lane = threadIdx.x;
  if (t >= 0){
    const uint4* src = (const uint4*)(x1b + (long)t*KD);
    dst[lane*2]   = src[lane*2];
    dst[lane*2+1] = src[lane*2+1];
  } else {
    uint4 zz; zz.x = zz.y = zz.z = zz.w = 0;
    dst[lane*2] = zz; dst[lane*2+1] = zz;
  }
}

// ---------------- combine + LN2 -> output ----------------
__launch_bounds__(256)
__global__ void combine_ln2(const float* __restrict__ x1, const u16* __restrict__ oute,
    const int* __restrict__ dest0, const int* __restrict__ dest1,
    const float* __restrict__ gate0, const float* __restrict__ gate1,
    const float* __restrict__ lnw, const float* __restrict__ lnb, float* __restrict__ out){
  const int t = blockIdx.x, tid = threadIdx.x;
  const int lane = tid & 63, wid = tid >> 6;
  float4 xv = ((const float4*)(x1 + (long)t*KD))[tid];
  int d0 = dest0[t], d1 = dest1[t];
  float g0 = gate0[t], g1 = gate1[t];
  if (d0 >= 0){
    ushort4 o = ((const ushort4*)(oute + (long)d0*KD))[tid];
    xv.x += g0*bf2f(o.x); xv.y += g0*bf2f(o.y); xv.z += g0*bf2f(o.z); xv.w += g0*bf2f(o.w);
  }
  if (d1 >= 0){
    ushort4 o = ((const ushort4*)(oute + (long)d1*KD))[tid];
    xv.x += g1*bf2f(o.x); xv.y += g1*bf2f(o.y); xv.z += g1*bf2f(o.z); xv.w += g1*bf2f(o.w);
  }
  float s  = xv.x + xv.y + xv.z + xv.w;
  float ss = xv.x*xv.x + xv.y*xv.y + xv.z*xv.z + xv.w*xv.w;
  for (int off = 32; off; off >>= 1){ s += __shfl_xor(s, off); ss += __shfl_xor(ss, off); }
  __shared__ float rs[4], rss[4];
  if (lane == 0){ rs[wid] = s; rss[wid] = ss; }
  __syncthreads();
  float S1 = rs[0]+rs[1]+rs[2]+rs[3];
  float S2 = rss[0]+rss[1]+rss[2]+rss[3];
  float mean = S1 * (1.0f/KD);
  float var  = S2 * (1.0f/KD) - mean*mean;
  float rstd = rsqrtf(var + 1e-5f);
  float4 w4 = ((const float4*)lnw)[tid];
  float4 b4 = ((const float4*)lnb)[tid];
  float4 yo;
  yo.x = (xv.x - mean)*rstd*w4.x + b4.x;
  yo.y = (xv.y - mean)*rstd*w4.y + b4.y;
  yo.z = (xv.z - mean)*rstd*w4.z + b4.z;
  yo.w = (xv.w - mean)*rstd*w4.w + b4.w;
  ((float4*)(out + (long)t*KD))[tid] = yo;
}

// ---------------- aux: tree-reduce per-token probs + lse^2, then scalar ----------------
__launch_bounds__(1024)
__global__ void aux_k(const int* __restrict__ cnt0, const float* __restrict__ ptok,
                      const float* __restrict__ lset, float* __restrict__ out){
  int t = threadIdx.x;
  float ps[8] = {0,0,0,0,0,0,0,0};
  float l2 = 0.f;
  for (int i = t; i < KN; i += 1024){
    const float4* p = (const float4*)(ptok + (long)i*8);
    float4 a = p[0], b = p[1];
    ps[0]+=a.x; ps[1]+=a.y; ps[2]+=a.z; ps[3]+=a.w;
    ps[4]+=b.x; ps[5]+=b.y; ps[6]+=b.z; ps[7]+=b.w;
    float l = lset[i]; l2 = fmaf(l, l, l2);
  }
#pragma unroll
  for (int off = 32; off; off >>= 1){
#pragma unroll
    for (int e = 0; e < 8; ++e) ps[e] += __shfl_xor(ps[e], off);
    l2 += __shfl_xor(l2, off);
  }
  __shared__ float sp[16][9];
  int lane = t & 63, wid = t >> 6;
  if (lane == 0){
#pragma unroll
    for (int e = 0; e < 8; ++e) sp[wid][e] = ps[e];
    sp[wid][8] = l2;
  }
  __syncthreads();
  if (t == 0){
    float fin[9];
#pragma unroll
    for (int j = 0; j < 9; ++j){
      float s = 0.f;
      for (int w2 = 0; w2 < 16; ++w2) s += sp[w2][j];
      fin[j] = s;
    }
    float bal = 0.f;
    for (int e = 0; e < 8; ++e)
      bal += ((float)cnt0[e] * (1.0f/KN)) * (fin[e] * (1.0f/KN));
    bal *= (float)KE;
    float zl = fin[8] * (1.0f/KN);
    out[(long)KN*KD] = 0.01f*bal + 0.001f*zl;
  }
}

// ---------------- host ----------------
extern "C" void kernel_launch(void* const* d_in, const int* in_sizes, int n_in,
                              void* d_out, int out_size, void* d_ws, size_t ws_size,
                              hipStream_t stream){
  const float* q    = (const float*)d_in[0];
  const float* k    = (const float*)d_in[1];
  const float* v    = (const float*)d_in[2];
  const float* inw  = (const float*)d_in[3];
  const float* inb  = (const float*)d_in[4];
  const float* outw = (const float*)d_in[5];
  const float* outb = (const float*)d_in[6];
  const float* ln1w = (const float*)d_in[7];
  const float* ln1b = (const float*)d_in[8];
  const float* ln2w = (const float*)d_in[9];
  const float* ln2b = (const float*)d_in[10];
  const float* rw   = (const float*)d_in[11];
  const float* w1   = (const float*)d_in[12];
  const float* b1   = (const float*)d_in[13];
  const float* w2   = (const float*)d_in[14];
  const float* b2   = (const float*)d_in[15];
  float* out = (float*)d_out;
  char* ws = (char*)d_ws;

  constexpr size_t PLB  = (size_t)KN*KD*2;            // 8,388,608 plane bytes
  constexpr long   PLE  = (long)KN*KD;                // plane elements
  constexpr size_t oW1T = 0;
  constexpr size_t oW2T = oW1T + 67108864;
  constexpr size_t oWQh = oW2T + 67108864;
  constexpr size_t oWQm = oWQh + 6291456;
  constexpr size_t oWQl = oWQm + 6291456;
  constexpr size_t oWOh = oWQl + 6291456;
  constexpr size_t oWOm = oWOh + 2097152;
  constexpr size_t oWOl = oWOm + 2097152;
  constexpr size_t oX1  = oWOl + 2097152;
  constexpr size_t oX1B = oX1  + 16777216;
  constexpr size_t oMISC= oX1B + 8388608;
  constexpr size_t oU1  = oMISC + 1048576;
  constexpr size_t oU2  = oU1 + 83886080;
  constexpr size_t oU3  = oU2 + 75497472;
  constexpr size_t oEND = oU3 + 41943040;    // ~369 MiB
  if (ws_size < oEND) return;

  u16* W1T = (u16*)(ws + oW1T);
  u16* W2T = (u16*)(ws + oW2T);
  u16* WQh = (u16*)(ws + oWQh); u16* WQm = (u16*)(ws + oWQm); u16* WQl = (u16*)(ws + oWQl);
  u16* WOh = (u16*)(ws + oWOh); u16* WOm = (u16*)(ws + oWOm); u16* WOl = (u16*)(ws + oWOl);
  float* X1 = (float*)(ws + oX1);
  u16* X1B  = (u16*)(ws + oX1B);

  int*   IDX0 = (int*)(ws + oMISC);
  int*   IDX1 = (int*)(ws + oMISC + 16384);
  int*   RNK0 = (int*)(ws + oMISC + 32768);
  int*   RNK1 = (int*)(ws + oMISC + 49152);
  int*   DST0 = (int*)(ws + oMISC + 65536);
  int*   DST1 = (int*)(ws + oMISC + 81920);
  float* G0   = (float*)(ws + oMISC + 98304);
  float* G1   = (float*)(ws + oMISC + 114688);
  int*   H0   = (int*)(ws + oMISC + 131072);
  int*   H1   = (int*)(ws + oMISC + 133120);
  int*   BS0  = (int*)(ws + oMISC + 135168);
  int*   BS1  = (int*)(ws + oMISC + 137216);
  int*   CNT0 = (int*)(ws + oMISC + 139264);
  int*   SLOT = (int*)(ws + oMISC + 139776);
  float* PTOK = (float*)(ws + oMISC + 262144);   // 4096*8 f32
  float* LSET = (float*)(ws + oMISC + 393216);   // 4096 f32

  u16* Qs0 = (u16*)(ws + oU1);           u16* Qs1 = (u16*)(ws + oU1 + PLB);   u16* Qs2 = (u16*)(ws + oU1 + 2*PLB);
  u16* Ks0 = (u16*)(ws + oU1 + 3*PLB);   u16* Ks1 = (u16*)(ws + oU1 + 4*PLB); u16* Ks2 = (u16*)(ws + oU1 + 5*PLB);
  u16* Vs0 = (u16*)(ws + oU1 + 6*PLB);   u16* Vs1 = (u16*)(ws + oU1 + 7*PLB); u16* Vs2 = (u16*)(ws + oU1 + 8*PLB);
  float* ATTN = (float*)(ws + oU1);                          // reuse after splits die
  u16* O30 = (u16*)(ws + oU1 + 16777216);
  u16* O31 = (u16*)(ws + oU1 + 16777216 + PLB);
  u16* O32 = (u16*)(ws + oU1 + 16777216 + 2*PLB);
  u16* HBUF = (u16*)(ws + oU1);                              // reuse for FFN h

  u16* QH0 = (u16*)(ws + oU2);
  u16* KH0 = (u16*)(ws + oU2 + 3*PLB);
  u16* KH1 = (u16*)(ws + oU2 + 4*PLB);
  u16* KH2 = (u16*)(ws + oU2 + 5*PLB);
  u16* QH1 = (u16*)(ws + oU2 + PLB);
  u16* QH2 = (u16*)(ws + oU2 + 2*PLB);
  u16* VT0 = (u16*)(ws + oU2 + 6*PLB);   u16* VT1 = (u16*)(ws + oU2 + 7*PLB); u16* VT2 = (u16*)(ws + oU2 + 8*PLB);
  u16* XIN  = (u16*)(ws + oU2);                              // reuse after attention
  u16* OUTE = (u16*)(ws + oU2 + 20971520);

  float* SCF = (float*)(ws + oU3);
  u16* PH  = (u16*)(ws + oU3 + 16777216);
  u16* PM  = (u16*)(ws + oU3 + 16777216 + PLB);
  u16* PLo = (u16*)(ws + oU3 + 16777216 + 2*PLB);

  hipMemsetAsync(ws + oMISC + 139776, 0xFF, (size_t)KE*KCAP*4, stream);

  // splits (3-plane bf16)
  split3k<<<4096, 256, 0, stream>>>(q, Qs0, Qs1, Qs2, (long)KN*KD/4);
  split3k<<<4096, 256, 0, stream>>>(k, Ks0, Ks1, Ks2, (long)KN*KD/4);
  split3k<<<4096, 256, 0, stream>>>(v, Vs0, Vs1, Vs2, (long)KN*KD/4);
  split3k<<<3072, 256, 0, stream>>>(inw, WQh, WQm, WQl, 786432);
  split3k<<<1024, 256, 0, stream>>>(outw, WOh, WOm, WOl, 262144);

  // weight transposes to (N,K) bf16 for NT GEMM
  trans_b<<<dim3(KDFF/32, KD/32, KE), dim3(32,8), 0, stream>>>(w1, W1T, KD, KDFF);
  trans_b<<<dim3(KD/32, KDFF/32, KE), dim3(32,8), 0, stream>>>(w2, W2T, KDFF, KD);

  // fused QKV projections (z=0:Q, 1:K, 2:V), 3-plane 6-term, 128-tile
  {
    GArgs ga{};
    ga.Ah=Qs0; ga.Am=Qs1; ga.Al=Qs2; ga.lda=KD; ga.sA=3*PLE;
    ga.Bh=WQh; ga.Bm=WQm; ga.Bl=WQl; ga.ldb=KD; ga.sB=1048576;
    ga.bias=inb; ga.biasStride=KD;
    ga.o0=QH0; ga.o1=nullptr; ga.o2=nullptr; ga.outF=nullptr;
    ga.K=KD; ga.mode=7; ga.chunkBase=0; ga.scale=1.f;
    gemm128<true><<<dim3(8, 32, 3), 256, 0, stream>>>(ga);
  }

  // attention, chunked over bh
  for (int c = 0; c < KNCH; ++c){
    long hoff = (long)c * KCHB * KS * KDH;
    GArgs gs{};
    gs.Ah=QH0+hoff; gs.Am=QH1+hoff; gs.Al=QH2+hoff; gs.lda=KDH; gs.sA=(long)KS*KDH;
    gs.Bh=KH0+hoff; gs.Bm=KH1+hoff; gs.Bl=KH2+hoff; gs.ldb=KDH; gs.sB=(long)KS*KDH;
    gs.bias=nullptr; gs.biasStride=0; gs.outF=SCF; gs.o0=gs.o1=gs.o2=nullptr;
    gs.K=KDH; gs.mode=2; gs.chunkBase=0; gs.scale=0.125f;
    gemm128<true><<<dim3(4, 4, KCHB), 256, 0, stream>>>(gs);

    softmax3<<<KCHB*KS, 64, 0, stream>>>(SCF, PH, PM, PLo);

    GArgs gp{};
    gp.Ah=PH; gp.Am=PM; gp.Al=PLo; gp.lda=KS; gp.sA=(long)KS*KS;
    gp.Bh=VT0+hoff; gp.Bm=VT1+hoff; gp.Bl=VT2+hoff; gp.ldb=KS; gp.sB=(long)KDH*KS;
    gp.bias=nullptr; gp.biasStride=0; gp.outF=nullptr;
    gp.o0=O30; gp.o1=O31; gp.o2=O32;
    gp.K=KS; gp.mode=3; gp.chunkBase=c*KCHB; gp.scale=1.f;
    gemm_nt<true><<<dim3(1, 8, KCHB), 64, 0, stream>>>(gp);
  }

  // out-projection (3-plane 6-term, 128-tile) -> ATTN fp32
  {
    GArgs go{};
    go.Ah=O30; go.Am=O31; go.Al=O32; go.lda=KD; go.sA=0;
    go.Bh=WOh; go.Bm=WOm; go.Bl=WOl; go.ldb=KD; go.sB=0;
    go.bias=outb; go.biasStride=0; go.outF=ATTN; go.o0=go.o1=go.o2=nullptr;
    go.K=KD; go.mode=4; go.chunkBase=0; go.scale=1.f;
    gemm128<true><<<dim3(8, 32, 1), 256, 0, stream>>>(go);
  }

  // LN1 + router (no contended atomics)
  ln1_router<<<KN, 256, 0, stream>>>(q, ATTN, ln1w, ln1b, rw, X1, X1B,
                                     IDX0, IDX1, G0, G1, PTOK, LSET);
  // capacity-ordered routing
  scan1<<<64, 64, 0, stream>>>(IDX0, IDX1, RNK0, RNK1, H0, H1);
  scan2<<<1, 64, 0, stream>>>(H0, H1, BS0, BS1, CNT0);
  scan3<<<16, 256, 0, stream>>>(IDX0, IDX1, RNK0, RNK1, BS0, BS1, DST0, DST1, SLOT);
  aux_k<<<1, 1024, 0, stream>>>(CNT0, PTOK, LSET, out);
  gather_xin<<<KE*KCAP, 64, 0, stream>>>(SLOT, X1B, XIN);

  // expert FFN (plain bf16, 128-tile)
  {
    GArgs f1{};
    f1.Ah=XIN; f1.Am=nullptr; f1.Al=nullptr; f1.lda=KD; f1.sA=(long)KCAP*KD;
    f1.Bh=W1T; f1.Bm=nullptr; f1.Bl=nullptr; f1.ldb=KD; f1.sB=(long)KDFF*KD;
    f1.bias=b1; f1.biasStride=KDFF; f1.outF=nullptr; f1.o0=HBUF; f1.o1=f1.o2=nullptr;
    f1.K=KD; f1.mode=5; f1.chunkBase=0; f1.scale=1.f;
    gemm128<false><<<dim3(KDFF/128, KCAP/128, KE), 256, 0, stream>>>(f1);

    GArgs f2{};
    f2.Ah=HBUF; f2.Am=nullptr; f2.Al=nullptr; f2.lda=KDFF; f2.sA=(long)KCAP*KDFF;
    f2.Bh=W2T; f2.Bm=nullptr; f2.Bl=nullptr; f2.ldb=KDFF; f2.sB=(long)KD*KDFF;
    f2.bias=b2; f2.biasStride=KD; f2.outF=nullptr; f2.o0=OUTE; f2.o1=f2.o2=nullptr;
    f2.K=KDFF; f2.mode=6; f2.chunkBase=0; f2.scale=1.f;
    gemm128<false><<<dim3(KD/128, KCAP/128, KE), 256, 0, stream>>>(f2);
  }

  // combine + LN2 -> output, plus aux
  combine_ln2<<<KN, 256, 0, stream>>>(X1, OUTE, DST0, DST1, G0, G1, ln2w, ln2b, out);
}

// Round 3
// 1345.373 us; speedup vs baseline: 1.9606x; 1.2151x over previous
//
#include <hip/hip_runtime.h>
#include <cstdint>
#include <cstddef>

// ---------------- constants ----------------
#define KB   8
#define KS   512
#define KD   1024
#define KH   16
#define KDH  64
#define KE   8
#define KDFF 4096
#define KN   4096      // B*S tokens
#define KCAP 1280      // ceil(2*4096/8*1.25)
#define KCHB 32        // attention bh per chunk
#define KNCH 4         // 128 / KCHB

typedef unsigned short u16;
typedef _Float16 f16;
typedef f16   f16x8 __attribute__((ext_vector_type(8)));
typedef float f32x4 __attribute__((ext_vector_type(4)));

#define RSCALE 4096.0f
#define RINV   2.44140625e-4f   // 1/4096

__device__ __forceinline__ u16 f2h(float f){
  f16 h = (f16)f;
  return __builtin_bit_cast(u16, h);
}
__device__ __forceinline__ float h2f(u16 u){
  f16 h = __builtin_bit_cast(f16, u);
  return (float)h;
}
// 2-plane f16 split; residual plane pre-scaled x4096 so it stays in f16
// normal range (guards against possible MFMA denorm-input flush).
__device__ __forceinline__ void split2v(float f, u16 &a, u16 &b){
  f16 h0 = (f16)f;
  float r = (f - (float)h0) * RSCALE;
  a = __builtin_bit_cast(u16, h0);
  b = f2h(r);
}
__device__ __forceinline__ f16x8 ld8h(const u16* p){
  uint4 v = *(const uint4*)p;
  return __builtin_bit_cast(f16x8, v);
}
// async global->LDS, 16B per lane; lds ptr must be wave-uniform (HW adds lane*16)
__device__ __forceinline__ void async16(const u16* g, u16* l){
  __builtin_amdgcn_global_load_lds(
      (const __attribute__((address_space(1))) unsigned int*)(g),
      (__attribute__((address_space(3))) unsigned int*)(l),
      16, 0, 0);
}

struct GArgs {
  const u16 *A0, *A1;
  const u16 *B0, *B1;
  long lda, sA, ldb, sB;         // element strides
  const float* bias; long biasStride;
  float* outF;
  u16 *o0;
  int K, mode;
  float scale;
};

// ---------------- 128x128 4-wave GEMM, LDS staged via global_load_lds ----------
// NP=2: A,B are (main, residual*4096) f16 planes; 3-term product ~ fp32 accuracy.
// LDS per plane: 128 rows x 32 cols f16, chunk-slot XOR swizzle (conflict-free, R2 PMC).
template<int NP>
__launch_bounds__(256)
__global__ void gemm128(GArgs g){
  __shared__ __align__(16) u16 sm[NP*2*4096];
  const int tid  = threadIdx.x;
  const int lane = tid & 63;
  const int wave = tid >> 6;
  const int quad = lane >> 4;
  const int r    = lane & 15;
  const int wm = (wave & 1) * 64;
  const int wn = (wave >> 1) * 64;
  const int z  = blockIdx.z;
  const long m0 = (long)blockIdx.y * 128;
  const long n0 = (long)blockIdx.x * 128;
  const u16* Ap[NP]; const u16* Bp[NP];
  Ap[0] = g.A0 + (long)z*g.sA; Bp[0] = g.B0 + (long)z*g.sB;
  if (NP == 2){ Ap[1] = g.A1 + (long)z*g.sA; Bp[1] = g.B1 + (long)z*g.sB; }
  const int srow   = tid >> 2;
  const int schunk = (tid & 3) ^ ((tid >> 3) & 3);
  f32x4 acc[4][4] = {};
  f32x4 accr[4][4] = {};          // cross-term accumulator (NP==2 only; elided otherwise)
  for (int kt = 0; kt < g.K; kt += 32){
#pragma unroll
    for (int p = 0; p < NP; ++p){
#pragma unroll
      for (int r0 = 0; r0 < 2; ++r0){
        long row = r0*64 + srow;
        async16(Ap[p] + (m0 + row)*g.lda + kt + schunk*8, &sm[p*4096      + r0*2048 + wave*512]);
        async16(Bp[p] + (n0 + row)*g.ldb + kt + schunk*8, &sm[(NP+p)*4096 + r0*2048 + wave*512]);
      }
    }
    __syncthreads();
    f16x8 af[NP][4], bf[NP][4];
#pragma unroll
    for (int i = 0; i < 4; ++i){
      int row = wm + i*16 + r;
      int slot = quad ^ ((row >> 1) & 3);
#pragma unroll
      for (int p = 0; p < NP; ++p)
        af[p][i] = ld8h(&sm[p*4096 + row*32 + slot*8]);
    }
#pragma unroll
    for (int j = 0; j < 4; ++j){
      int row = wn + j*16 + r;
      int slot = quad ^ ((row >> 1) & 3);
#pragma unroll
      for (int p = 0; p < NP; ++p)
        bf[p][j] = ld8h(&sm[(NP+p)*4096 + row*32 + slot*8]);
    }
#pragma unroll
    for (int i = 0; i < 4; ++i)
#pragma unroll
      for (int j = 0; j < 4; ++j){
        acc[i][j] = __builtin_amdgcn_mfma_f32_16x16x32_f16(af[0][i], bf[0][j], acc[i][j], 0, 0, 0);
        if (NP == 2){
          accr[i][j] = __builtin_amdgcn_mfma_f32_16x16x32_f16(af[0][i], bf[1][j], accr[i][j], 0, 0, 0);
          accr[i][j] = __builtin_amdgcn_mfma_f32_16x16x32_f16(af[1][i], bf[0][j], accr[i][j], 0, 0, 0);
        }
      }
    __syncthreads();
  }
  // epilogue: C/D layout col=lane&15, row=quad*4+reg
#pragma unroll
  for (int i = 0; i < 4; ++i){
#pragma unroll
    for (int rr = 0; rr < 4; ++rr){
      long row = m0 + wm + i*16 + quad*4 + rr;
#pragma unroll
      for (int j = 0; j < 4; ++j){
        long col = n0 + wn + j*16 + r;
        float v = acc[i][j][rr];
        if (NP == 2) v += accr[i][j][rr] * RINV;
        switch (g.mode){
          case 2: {               // scores (scaled, fp32)
            g.outF[((long)z*KS + row)*KS + col] = v * g.scale;
            break;
          }
          case 4: {               // out-proj: +bias, fp32
            v += g.bias[col];
            g.outF[row*KD + col] = v;
            break;
          }
          case 5: {               // FFN1: +b1, gelu(tanh approx), f16
            v += g.bias[(long)z*g.biasStride + col];
            float u = v + 0.044715f*v*v*v;
            v = 0.5f*v*(1.0f + tanhf(0.7978845608028654f*u));
            g.o0[((long)z*KCAP + row)*KDFF + col] = f2h(v);
            break;
          }
          case 6: {               // FFN2: +b2, f16
            v += g.bias[(long)z*g.biasStride + col];
            g.o0[((long)z*KCAP + row)*KD + col] = f2h(v);
            break;
          }
          default: {              // mode 7: fused QKV -> head layout, 2-plane split
            v += g.bias[(long)z*g.biasStride + col];
            long b = row >> 9, s = row & 511;
            long h = col >> 6, d = col & 63;
            long idx = (z < 2) ? (((b*KH + h)*KS + s)*KDH + d)    // Q,K: (B,H,S,dh)
                               : (((b*KH + h)*KDH + d)*KS + s);   // V:   (B,H,dh,S)
            u16* d0 = g.o0 + (long)z * 2 * ((long)KN*KD);
            u16* d1 = d0 + (long)KN*KD;
            unsigned short x, y; split2v(v, x, y);
            d0[idx] = x; d1[idx] = y;
            break;
          }
        }
      }
    }
  }
}

// ---------------- PV GEMM: per bh, O[512,64] = P[512,512] @ Vt[64,512]^T ---------
// Block tile 128x64, 4 waves as 2(M)x2(N of 32); f16 2-plane 3-term.
__launch_bounds__(256)
__global__ void gemm_pv(const u16* __restrict__ Ph, const u16* __restrict__ Pl,
                        const u16* __restrict__ V0, const u16* __restrict__ V1,
                        u16* __restrict__ O0, u16* __restrict__ O1, int chunkBase){
  __shared__ __align__(16) u16 sm[2*4096 + 2*2048];   // A 2x8KB + B 2x4KB = 24KB
  const int tid  = threadIdx.x;
  const int lane = tid & 63;
  const int wave = tid >> 6;
  const int quad = lane >> 4;
  const int r    = lane & 15;
  const int wm = (wave & 1) * 64;
  const int wn = (wave >> 1) * 32;
  const int z  = blockIdx.y;
  const long m0 = (long)blockIdx.x * 128;
  const u16* Ap[2] = { Ph + (long)z*KS*KS,  Pl + (long)z*KS*KS };
  const u16* Bp[2] = { V0 + (long)z*KDH*KS, V1 + (long)z*KDH*KS };
  const int srow   = tid >> 2;
  const int schunk = (tid & 3) ^ ((tid >> 3) & 3);
  f32x4 acc[4][2] = {};
  f32x4 accr[4][2] = {};
  for (int kt = 0; kt < KS; kt += 32){
#pragma unroll
    for (int p = 0; p < 2; ++p){
#pragma unroll
      for (int r0 = 0; r0 < 2; ++r0){
        long row = r0*64 + srow;
        async16(Ap[p] + (m0 + row)*KS + kt + schunk*8, &sm[p*4096 + r0*2048 + wave*512]);
      }
      async16(Bp[p] + srow*KS + kt + schunk*8, &sm[8192 + p*2048 + wave*512]);
    }
    __syncthreads();
    f16x8 af[2][4], bf[2][2];
#pragma unroll
    for (int i = 0; i < 4; ++i){
      int row = wm + i*16 + r;
      int slot = quad ^ ((row >> 1) & 3);
#pragma unroll
      for (int p = 0; p < 2; ++p)
        af[p][i] = ld8h(&sm[p*4096 + row*32 + slot*8]);
    }
#pragma unroll
    for (int j = 0; j < 2; ++j){
      int row = wn + j*16 + r;
      int slot = quad ^ ((row >> 1) & 3);
#pragma unroll
      for (int p = 0; p < 2; ++p)
        bf[p][j] = ld8h(&sm[8192 + p*2048 + row*32 + slot*8]);
    }
#pragma unroll
    for (int i = 0; i < 4; ++i)
#pragma unroll
      for (int j = 0; j < 2; ++j){
        acc[i][j]  = __builtin_amdgcn_mfma_f32_16x16x32_f16(af[0][i], bf[0][j], acc[i][j], 0, 0, 0);
        accr[i][j] = __builtin_amdgcn_mfma_f32_16x16x32_f16(af[0][i], bf[1][j], accr[i][j], 0, 0, 0);
        accr[i][j] = __builtin_amdgcn_mfma_f32_16x16x32_f16(af[1][i], bf[0][j], accr[i][j], 0, 0, 0);
      }
    __syncthreads();
  }
  int bh = chunkBase + z;
  long b = bh >> 4, h = bh & 15;
#pragma unroll
  for (int i = 0; i < 4; ++i){
#pragma unroll
    for (int rr = 0; rr < 4; ++rr){
      long s = m0 + wm + i*16 + quad*4 + rr;
#pragma unroll
      for (int j = 0; j < 2; ++j){
        long col = wn + j*16 + r;
        float v = acc[i][j][rr] + accr[i][j][rr] * RINV;
        long idx = (b*KS + s)*KD + h*KDH + col;
        unsigned short x, y; split2v(v, x, y);
        O0[idx] = x; O1[idx] = y;
      }
    }
  }
}

// ---------------- prep kernels ----------------
__global__ void split2k(const float* __restrict__ x, u16* __restrict__ h,
                        u16* __restrict__ l, long n4){
  long i = (long)blockIdx.x*blockDim.x + threadIdx.x;
  if (i >= n4) return;
  float4 v = ((const float4*)x)[i];
  ushort4 a, b;
  split2v(v.x, a.x, b.x);
  split2v(v.y, a.y, b.y);
  split2v(v.z, a.z, b.z);
  split2v(v.w, a.w, b.w);
  ((ushort4*)h)[i] = a; ((ushort4*)l)[i] = b;
}

// batched transpose: in (z,R,C) f32 -> out (z,C,R) f16
__global__ void trans_b(const float* __restrict__ in, u16* __restrict__ outp, int R, int Cc){
  __shared__ float tile[32][33];
  long z = blockIdx.z;
  const float* ip = in + z*(long)R*Cc;
  u16* op = outp + z*(long)R*Cc;
  int c0 = blockIdx.x*32, r0 = blockIdx.y*32;
  int tx = threadIdx.x, ty = threadIdx.y;
  for (int rr = ty; rr < 32; rr += 8)
    tile[rr][tx] = ip[(long)(r0+rr)*Cc + c0 + tx];
  __syncthreads();
  for (int cc = ty; cc < 32; cc += 8)
    op[(long)(c0+cc)*R + r0 + tx] = f2h(tile[tx][cc]);
}

// ---------------- softmax over 512-wide rows -> 2-plane f16 P ----------------
__launch_bounds__(64)
__global__ void softmax2(const float* __restrict__ scores, u16* __restrict__ ph,
                         u16* __restrict__ pl){
  long row = blockIdx.x;
  const float* rp = scores + row * KS;
  int lane = threadIdx.x;
  float4 a = ((const float4*)rp)[lane*2];
  float4 b = ((const float4*)rp)[lane*2 + 1];
  float vv[8] = {a.x,a.y,a.z,a.w,b.x,b.y,b.z,b.w};
  float m = vv[0];
#pragma unroll
  for (int t = 1; t < 8; ++t) m = fmaxf(m, vv[t]);
  for (int off = 32; off; off >>= 1) m = fmaxf(m, __shfl_xor(m, off));
  float s = 0.f;
#pragma unroll
  for (int t = 0; t < 8; ++t){ vv[t] = expf(vv[t] - m); s += vv[t]; }
  for (int off = 32; off; off >>= 1) s += __shfl_xor(s, off);
  float inv = 1.0f / s;
  unsigned short hh[8], ll[8];
#pragma unroll
  for (int t = 0; t < 8; ++t) split2v(vv[t] * inv, hh[t], ll[t]);
  ushort4* dh = (ushort4*)(ph + row*KS + lane*8);
  dh[0] = make_ushort4(hh[0],hh[1],hh[2],hh[3]);
  dh[1] = make_ushort4(hh[4],hh[5],hh[6],hh[7]);
  ushort4* dl = (ushort4*)(pl + row*KS + lane*8);
  dl[0] = make_ushort4(ll[0],ll[1],ll[2],ll[3]);
  dl[1] = make_ushort4(ll[4],ll[5],ll[6],ll[7]);
}

// ---------------- LN1 + router (fp32 exact; no contended atomics) ----------------
__launch_bounds__(256)
__global__ void ln1_router(const float* __restrict__ q, const float* __restrict__ attn,
    const float* __restrict__ lnw, const float* __restrict__ lnb, const float* __restrict__ rw,
    float* __restrict__ x1, u16* __restrict__ x1b,
    int* __restrict__ idx0, int* __restrict__ idx1, float* __restrict__ gate0, float* __restrict__ gate1,
    float* __restrict__ ptok, float* __restrict__ lset){
  const int t = blockIdx.x, tid = threadIdx.x;
  const int lane = tid & 63, wid = tid >> 6;
  float4 xv = ((const float4*)(q    + (long)t*KD))[tid];
  float4 av = ((const float4*)(attn + (long)t*KD))[tid];
  xv.x += av.x; xv.y += av.y; xv.z += av.z; xv.w += av.w;
  float s  = xv.x + xv.y + xv.z + xv.w;
  float ss = xv.x*xv.x + xv.y*xv.y + xv.z*xv.z + xv.w*xv.w;
  for (int off = 32; off; off >>= 1){ s += __shfl_xor(s, off); ss += __shfl_xor(ss, off); }
  __shared__ float rs[4], rss[4];
  if (lane == 0){ rs[wid] = s; rss[wid] = ss; }
  __syncthreads();
  float S1 = rs[0]+rs[1]+rs[2]+rs[3];
  float S2 = rss[0]+rss[1]+rss[2]+rss[3];
  float mean = S1 * (1.0f/KD);
  float var  = S2 * (1.0f/KD) - mean*mean;
  float rstd = rsqrtf(var + 1e-5f);
  float4 w4 = ((const float4*)lnw)[tid];
  float4 b4 = ((const float4*)lnb)[tid];
  float y0 = (xv.x - mean)*rstd*w4.x + b4.x;
  float y1 = (xv.y - mean)*rstd*w4.y + b4.y;
  float y2 = (xv.z - mean)*rstd*w4.z + b4.z;
  float y3 = (xv.w - mean)*rstd*w4.w + b4.w;
  float4 yo; yo.x=y0; yo.y=y1; yo.z=y2; yo.w=y3;
  ((float4*)(x1 + (long)t*KD))[tid] = yo;
  ushort4 yb; yb.x=f2h(y0); yb.y=f2h(y1); yb.z=f2h(y2); yb.w=f2h(y3);
  ((ushort4*)(x1b + (long)t*KD))[tid] = yb;
  int d0 = tid*4;
  float rloc[4][8];
#pragma unroll
  for (int c = 0; c < 4; ++c){
    const float4* rp = (const float4*)(rw + (long)(d0 + c)*KE);
    float4 u = rp[0], v2 = rp[1];
    rloc[c][0]=u.x; rloc[c][1]=u.y; rloc[c][2]=u.z; rloc[c][3]=u.w;
    rloc[c][4]=v2.x; rloc[c][5]=v2.y; rloc[c][6]=v2.z; rloc[c][7]=v2.w;
  }
  float yv[4] = {y0,y1,y2,y3};
  float pr[8];
#pragma unroll
  for (int e = 0; e < 8; ++e)
    pr[e] = yv[0]*rloc[0][e] + yv[1]*rloc[1][e] + yv[2]*rloc[2][e] + yv[3]*rloc[3][e];
#pragma unroll
  for (int e = 0; e < 8; ++e)
    for (int off = 32; off; off >>= 1) pr[e] += __shfl_xor(pr[e], off);
  __shared__ float wl[4][8];
  if (lane == 0)
#pragma unroll
    for (int e = 0; e < 8; ++e) wl[wid][e] = pr[e];
  __syncthreads();
  if (tid == 0){
    float lg[8];
#pragma unroll
    for (int e = 0; e < 8; ++e) lg[e] = wl[0][e]+wl[1][e]+wl[2][e]+wl[3][e];
    float mx = lg[0];
    for (int e = 1; e < 8; ++e) mx = fmaxf(mx, lg[e]);
    float pe[8], se = 0.f;
    for (int e = 0; e < 8; ++e){ pe[e] = expf(lg[e]-mx); se += pe[e]; }
    float inv = 1.0f/se;
    for (int e = 0; e < 8; ++e) pe[e] *= inv;
    int e0 = 0;
    for (int e = 1; e < 8; ++e) if (pe[e] > pe[e0]) e0 = e;   // first-index tie break (jax)
    int e1 = (e0 == 0) ? 1 : 0;
    for (int e = 0; e < 8; ++e) if (e != e0 && pe[e] > pe[e1]) e1 = e;
    idx0[t] = e0; idx1[t] = e1;
    gate0[t] = pe[e0]; gate1[t] = pe[e1];
    for (int e = 0; e < 8; ++e) ptok[(long)t*8 + e] = pe[e];
    lset[t] = mx + logf(se);
  }
}

// ---------------- routing scans ----------------
__launch_bounds__(64)
__global__ void scan1(const int* __restrict__ idx0, const int* __restrict__ idx1,
                      int* __restrict__ rnk0, int* __restrict__ rnk1,
                      int* __restrict__ h0, int* __restrict__ h1){
  int lane = threadIdx.x;
  int t = blockIdx.x*64 + lane;
  int i0 = idx0[t], i1 = idx1[t];
  unsigned long long below = (1ull << lane) - 1ull;
  unsigned long long b0[8], b1[8];
#pragma unroll
  for (int e = 0; e < 8; ++e){
    b0[e] = __ballot(i0 == e);
    b1[e] = __ballot(i1 == e);
  }
  rnk0[t] = __popcll(b0[i0] & below);
  rnk1[t] = __popcll(b1[i1] & below);
  if (lane < 8){
    h0[blockIdx.x*8 + lane] = __popcll(b0[lane]);
    h1[blockIdx.x*8 + lane] = __popcll(b1[lane]);
  }
}

__launch_bounds__(64)
__global__ void scan2(const int* __restrict__ h0, const int* __restrict__ h1,
                      int* __restrict__ bs0, int* __restrict__ bs1, int* __restrict__ cnt0){
  int lane = threadIdx.x;  // lane = chunk id (64 chunks)
  for (int e = 0; e < 8; ++e){
    int v = h0[lane*8 + e];
    int x = v;
    for (int off = 1; off < 64; off <<= 1){
      int y = __shfl_up(x, off);
      if (lane >= off) x += y;
    }
    bs0[lane*8 + e] = x - v;
    int tot = __shfl(x, 63);
    if (lane == 0) cnt0[e] = tot;
    int w = h1[lane*8 + e];
    int xx = w;
    for (int off = 1; off < 64; off <<= 1){
      int y = __shfl_up(xx, off);
      if (lane >= off) xx += y;
    }
    bs1[lane*8 + e] = tot + xx - w;
  }
}

__global__ void scan3(const int* __restrict__ idx0, const int* __restrict__ idx1,
                      const int* __restrict__ rnk0, const int* __restrict__ rnk1,
                      const int* __restrict__ bs0, const int* __restrict__ bs1,
                      int* __restrict__ dst0, int* __restrict__ dst1, int* __restrict__ slot){
  int t = blockIdx.x*blockDim.x + threadIdx.x;
  if (t >= KN) return;
  int c = t >> 6;
  int e0 = idx0[t], e1 = idx1[t];
  int p0 = bs0[c*8 + e0] + rnk0[t];
  int p1 = bs1[c*8 + e1] + rnk1[t];
  int d0 = (p0 < KCAP) ? (e0*KCAP + p0) : -1;
  int d1 = (p1 < KCAP) ? (e1*KCAP + p1) : -1;
  dst0[t] = d0; dst1[t] = d1;
  if (d0 >= 0) slot[d0] = t;
  if (d1 >= 0) slot[d1] = t;
}

// ---------------- gather xin ----------------
__launch_bounds__(64)
__global__ void gather_xin(const int* __restrict__ slot_token, const u16* __restrict__ x1b,
                           u16* __restrict__ xin){
  long slot = blockIdx.x;
  int t = slot_token[slot];
  uint4* dst = (uint4*)(xin + slot*KD);
  int lane = threadIdx.x;
  if (t >= 0){
    const uint4* src = (const uint4*)(x1b + (long)t*KD);
    dst[lane*2]   = src[lane*2];
    dst[lane*2+1] = src[lane*2+1];
  } else {
    uint4 zz; zz.x = zz.y = zz.z = zz.w = 0;
    dst[lane*2] = zz; dst[lane*2+1] = zz;
  }
}

// ---------------- combine + LN2 -> output ----------------
__launch_bounds__(256)
__global__ void combine_ln2(const float* __restrict__ x1, const u16* __restrict__ oute,
    const int* __restrict__ dest0, const int* __restrict__ dest1,
    const float* __restrict__ gate0, const float* __restrict__ gate1,
    const float* __restrict__ lnw, const float* __restrict__ lnb, float* __restrict__ out){
  const int t = blockIdx.x, tid = threadIdx.x;
  const int lane = tid & 63, wid = tid >> 6;
  float4 xv = ((const float4*)(x1 + (long)t*KD))[tid];
  int d0 = dest0[t], d1 = dest1[t];
  float g0 = gate0[t], g1 = gate1[t];
  if (d0 >= 0){
    ushort4 o = ((const ushort4*)(oute + (long)d0*KD))[tid];
    xv.x += g0*h2f(o.x); xv.y += g0*h2f(o.y); xv.z += g0*h2f(o.z); xv.w += g0*h2f(o.w);
  }
  if (d1 >= 0){
    ushort4 o = ((const ushort4*)(oute + (long)d1*KD))[tid];
    xv.x += g1*h2f(o.x); xv.y += g1*h2f(o.y); xv.z += g1*h2f(o.z); xv.w += g1*h2f(o.w);
  }
  float s  = xv.x + xv.y + xv.z + xv.w;
  float ss = xv.x*xv.x + xv.y*xv.y + xv.z*xv.z + xv.w*xv.w;
  for (int off = 32; off; off >>= 1){ s += __shfl_xor(s, off); ss += __shfl_xor(ss, off); }
  __shared__ float rs[4], rss[4];
  if (lane == 0){ rs[wid] = s; rss[wid] = ss; }
  __syncthreads();
  float S1 = rs[0]+rs[1]+rs[2]+rs[3];
  float S2 = rss[0]+rss[1]+rss[2]+rss[3];
  float mean = S1 * (1.0f/KD);
  float var  = S2 * (1.0f/KD) - mean*mean;
  float rstd = rsqrtf(var + 1e-5f);
  float4 w4 = ((const float4*)lnw)[tid];
  float4 b4 = ((const float4*)lnb)[tid];
  float4 yo;
  yo.x = (xv.x - mean)*rstd*w4.x + b4.x;
  yo.y = (xv.y - mean)*rstd*w4.y + b4.y;
  yo.z = (xv.z - mean)*rstd*w4.z + b4.z;
  yo.w = (xv.w - mean)*rstd*w4.w + b4.w;
  ((float4*)(out + (long)t*KD))[tid] = yo;
}

// ---------------- aux: tree-reduce per-token probs + lse^2 ----------------
__launch_bounds__(1024)
__global__ void aux_k(const int* __restrict__ cnt0, const float* __restrict__ ptok,
                      const float* __restrict__ lset, float* __restrict__ out){
  int t = threadIdx.x;
  float ps[8] = {0,0,0,0,0,0,0,0};
  float l2 = 0.f;
  for (int i = t; i < KN; i += 1024){
    const float4* p = (const float4*)(ptok + (long)i*8);
    float4 a = p[0], b = p[1];
    ps[0]+=a.x; ps[1]+=a.y; ps[2]+=a.z; ps[3]+=a.w;
    ps[4]+=b.x; ps[5]+=b.y; ps[6]+=b.z; ps[7]+=b.w;
    float l = lset[i]; l2 = fmaf(l, l, l2);
  }
#pragma unroll
  for (int off = 32; off; off >>= 1){
#pragma unroll
    for (int e = 0; e < 8; ++e) ps[e] += __shfl_xor(ps[e], off);
    l2 += __shfl_xor(l2, off);
  }
  __shared__ float sp[16][9];
  int lane = t & 63, wid = t >> 6;
  if (lane == 0){
#pragma unroll
    for (int e = 0; e < 8; ++e) sp[wid][e] = ps[e];
    sp[wid][8] = l2;
  }
  __syncthreads();
  if (t == 0){
    float fin[9];
#pragma unroll
    for (int j = 0; j < 9; ++j){
      float s = 0.f;
      for (int w2 = 0; w2 < 16; ++w2) s += sp[w2][j];
      fin[j] = s;
    }
    float bal = 0.f;
    for (int e = 0; e < 8; ++e)
      bal += ((float)cnt0[e] * (1.0f/KN)) * (fin[e] * (1.0f/KN));
    bal *= (float)KE;
    float zl = fin[8] * (1.0f/KN);
    out[(long)KN*KD] = 0.01f*bal + 0.001f*zl;
  }
}

// ---------------- host ----------------
extern "C" void kernel_launch(void* const* d_in, const int* in_sizes, int n_in,
                              void* d_out, int out_size, void* d_ws, size_t ws_size,
                              hipStream_t stream){
  const float* q    = (const float*)d_in[0];
  const float* k    = (const float*)d_in[1];
  const float* v    = (const float*)d_in[2];
  const float* inw  = (const float*)d_in[3];
  const float* inb  = (const float*)d_in[4];
  const float* outw = (const float*)d_in[5];
  const float* outb = (const float*)d_in[6];
  const float* ln1w = (const float*)d_in[7];
  const float* ln1b = (const float*)d_in[8];
  const float* ln2w = (const float*)d_in[9];
  const float* ln2b = (const float*)d_in[10];
  const float* rw   = (const float*)d_in[11];
  const float* w1   = (const float*)d_in[12];
  const float* b1   = (const float*)d_in[13];
  const float* w2   = (const float*)d_in[14];
  const float* b2   = (const float*)d_in[15];
  float* out = (float*)d_out;
  char* ws = (char*)d_ws;

  constexpr size_t PLB  = (size_t)KN*KD*2;            // 8,388,608 plane bytes
  constexpr long   PLE  = (long)KN*KD;                // plane elements
  constexpr size_t oW1T = 0;                          // 64 MB f16
  constexpr size_t oW2T = oW1T + 67108864;            // 64 MB f16
  constexpr size_t oWQ0 = oW2T + 67108864;            // 6 MB
  constexpr size_t oWQ1 = oWQ0 + 6291456;
  constexpr size_t oWO0 = oWQ1 + 6291456;             // 2 MB
  constexpr size_t oWO1 = oWO0 + 2097152;
  constexpr size_t oX1  = oWO1 + 2097152;             // 16 MB
  constexpr size_t oX1B = oX1  + 16777216;            // 8 MB
  constexpr size_t oMISC= oX1B + 8388608;             // 1 MB
  constexpr size_t oU1  = oMISC + 1048576;            // 84 MB: q/k/v splits -> ATTN+O planes -> HBUF
  constexpr size_t oU2  = oU1 + 83886080;             // 48 MB: qh/kh/vt -> xin + out_e
  constexpr size_t oU3  = oU2 + 50331648;             // 64 MB: SCF + P planes
  constexpr size_t oEND = oU3 + 67108864;             // ~361 MB (< round-1's 369 MB, OK)
  if (ws_size < oEND) return;

  u16* W1T = (u16*)(ws + oW1T);
  u16* W2T = (u16*)(ws + oW2T);
  u16* WQ0 = (u16*)(ws + oWQ0); u16* WQ1 = (u16*)(ws + oWQ1);
  u16* WO0 = (u16*)(ws + oWO0); u16* WO1 = (u16*)(ws + oWO1);
  float* X1 = (float*)(ws + oX1);
  u16* X1B  = (u16*)(ws + oX1B);

  int*   IDX0 = (int*)(ws + oMISC);
  int*   IDX1 = (int*)(ws + oMISC + 16384);
  int*   RNK0 = (int*)(ws + oMISC + 32768);
  int*   RNK1 = (int*)(ws + oMISC + 49152);
  int*   DST0 = (int*)(ws + oMISC + 65536);
  int*   DST1 = (int*)(ws + oMISC + 81920);
  float* G0   = (float*)(ws + oMISC + 98304);
  float* G1   = (float*)(ws + oMISC + 114688);
  int*   H0   = (int*)(ws + oMISC + 131072);
  int*   H1   = (int*)(ws + oMISC + 133120);
  int*   BS0  = (int*)(ws + oMISC + 135168);
  int*   BS1  = (int*)(ws + oMISC + 137216);
  int*   CNT0 = (int*)(ws + oMISC + 139264);
  int*   SLOT = (int*)(ws + oMISC + 139776);
  float* PTOK = (float*)(ws + oMISC + 262144);
  float* LSET = (float*)(ws + oMISC + 393216);

  u16* Qs0 = (u16*)(ws + oU1);           u16* Qs1 = (u16*)(ws + oU1 + PLB);
  u16* Ks0 = (u16*)(ws + oU1 + 2*PLB);   u16* Ks1 = (u16*)(ws + oU1 + 3*PLB);
  u16* Vs0 = (u16*)(ws + oU1 + 4*PLB);   u16* Vs1 = (u16*)(ws + oU1 + 5*PLB);
  float* ATTN = (float*)(ws + oU1);                          // 16 MB, after splits die
  u16* O0 = (u16*)(ws + oU1 + 16777216);
  u16* O1 = (u16*)(ws + oU1 + 16777216 + PLB);
  u16* HBUF = (u16*)(ws + oU1);                              // 80 MB, after ATTN/O die

  u16* QH0 = (u16*)(ws + oU2);           u16* QH1 = (u16*)(ws + oU2 + PLB);
  u16* KH0 = (u16*)(ws + oU2 + 2*PLB);   u16* KH1 = (u16*)(ws + oU2 + 3*PLB);
  u16* VT0 = (u16*)(ws + oU2 + 4*PLB);   u16* VT1 = (u16*)(ws + oU2 + 5*PLB);
  u16* XIN  = (u16*)(ws + oU2);                              // after attention
  u16* OUTE = (u16*)(ws + oU2 + 20971520);

  float* SCF = (float*)(ws + oU3);                           // 33.5 MB fp32
  u16* PH  = (u16*)(ws + oU3 + 33554432);
  u16* PL  = (u16*)(ws + oU3 + 50331648);

  hipMemsetAsync(ws + oMISC + 139776, 0xFF, (size_t)KE*KCAP*4, stream);

  // 2-plane f16 splits (residual plane scaled x4096)
  split2k<<<4096, 256, 0, stream>>>(q, Qs0, Qs1, (long)KN*KD/4);
  split2k<<<4096, 256, 0, stream>>>(k, Ks0, Ks1, (long)KN*KD/4);
  split2k<<<4096, 256, 0, stream>>>(v, Vs0, Vs1, (long)KN*KD/4);
  split2k<<<3072, 256, 0, stream>>>(inw, WQ0, WQ1, 786432);
  split2k<<<1024, 256, 0, stream>>>(outw, WO0, WO1, 262144);

  // FFN weight transposes to (N,K) f16 for NT GEMM
  trans_b<<<dim3(KDFF/32, KD/32, KE), dim3(32,8), 0, stream>>>(w1, W1T, KD, KDFF);
  trans_b<<<dim3(KD/32, KDFF/32, KE), dim3(32,8), 0, stream>>>(w2, W2T, KDFF, KD);

  // fused QKV projections (z=0:Q, 1:K, 2:V), f16 2-plane 3-term
  {
    GArgs ga{};
    ga.A0=Qs0; ga.A1=Qs1; ga.lda=KD; ga.sA=2*PLE;
    ga.B0=WQ0; ga.B1=WQ1; ga.ldb=KD; ga.sB=1048576;
    ga.bias=inb; ga.biasStride=KD;
    ga.o0=QH0; ga.outF=nullptr;
    ga.K=KD; ga.mode=7; ga.scale=1.f;
    gemm128<2><<<dim3(8, 32, 3), 256, 0, stream>>>(ga);
  }

  // attention, chunked over bh (4 chunks of 32)
  for (int c = 0; c < KNCH; ++c){
    long hoff = (long)c * KCHB * KS * KDH;
    GArgs gs{};
    gs.A0=QH0+hoff; gs.A1=QH1+hoff; gs.lda=KDH; gs.sA=(long)KS*KDH;
    gs.B0=KH0+hoff; gs.B1=KH1+hoff; gs.ldb=KDH; gs.sB=(long)KS*KDH;
    gs.bias=nullptr; gs.biasStride=0; gs.outF=SCF; gs.o0=nullptr;
    gs.K=KDH; gs.mode=2; gs.scale=0.125f;
    gemm128<2><<<dim3(4, 4, KCHB), 256, 0, stream>>>(gs);

    softmax2<<<KCHB*KS, 64, 0, stream>>>(SCF, PH, PL);

    gemm_pv<<<dim3(4, KCHB), 256, 0, stream>>>(PH, PL, VT0+hoff, VT1+hoff,
                                               O0, O1, c*KCHB);
  }

  // out-projection -> ATTN fp32
  {
    GArgs go{};
    go.A0=O0; go.A1=O1; go.lda=KD; go.sA=0;
    go.B0=WO0; go.B1=WO1; go.ldb=KD; go.sB=0;
    go.bias=outb; go.biasStride=0; go.outF=ATTN; go.o0=nullptr;
    go.K=KD; go.mode=4; go.scale=1.f;
    gemm128<2><<<dim3(8, 32, 1), 256, 0, stream>>>(go);
  }

  // LN1 + router
  ln1_router<<<KN, 256, 0, stream>>>(q, ATTN, ln1w, ln1b, rw, X1, X1B,
                                     IDX0, IDX1, G0, G1, PTOK, LSET);
  // capacity-ordered routing
  scan1<<<64, 64, 0, stream>>>(IDX0, IDX1, RNK0, RNK1, H0, H1);
  scan2<<<1, 64, 0, stream>>>(H0, H1, BS0, BS1, CNT0);
  scan3<<<16, 256, 0, stream>>>(IDX0, IDX1, RNK0, RNK1, BS0, BS1, DST0, DST1, SLOT);
  aux_k<<<1, 1024, 0, stream>>>(CNT0, PTOK, LSET, out);
  gather_xin<<<KE*KCAP, 64, 0, stream>>>(SLOT, X1B, XIN);

  // expert FFN (plain f16, 1-plane)
  {
    GArgs f1{};
    f1.A0=XIN; f1.A1=nullptr; f1.lda=KD; f1.sA=(long)KCAP*KD;
    f1.B0=W1T; f1.B1=nullptr; f1.ldb=KD; f1.sB=(long)KDFF*KD;
    f1.bias=b1; f1.biasStride=KDFF; f1.outF=nullptr; f1.o0=HBUF;
    f1.K=KD; f1.mode=5; f1.scale=1.f;
    gemm128<1><<<dim3(KDFF/128, KCAP/128, KE), 256, 0, stream>>>(f1);

    GArgs f2{};
    f2.A0=HBUF; f2.A1=nullptr; f2.lda=KDFF; f2.sA=(long)KCAP*KDFF;
    f2.B0=W2T; f2.B1=nullptr; f2.ldb=KDFF; f2.sB=(long)KD*KDFF;
    f2.bias=b2; f2.biasStride=KD; f2.outF=nullptr; f2.o0=OUTE;
    f2.K=KDFF; f2.mode=6; f2.scale=1.f;
    gemm128<1><<<dim3(KD/128, KCAP/128, KE), 256, 0, stream>>>(f2);
  }

  // combine + LN2 -> output
  combine_ln2<<<KN, 256, 0, stream>>>(X1, OUTE, DST0, DST1, G0, G1, ln2w, ln2b, out);
}